// Round 1
// baseline (141.434 us; speedup 1.0000x reference)
//
#include <hip/hip_runtime.h>

#define B_SZ 2
#define T_SZ 2048
#define C_SZ 1024
#define H_CNT 16
#define D_SZ 64
#define WIN 512

typedef __bf16 bf16_t;
typedef bf16_t bf16x8 __attribute__((ext_vector_type(8)));
typedef bf16_t bf16x4 __attribute__((ext_vector_type(4)));
typedef float f32x4 __attribute__((ext_vector_type(4)));

__device__ __forceinline__ f32x4 mfma16(bf16x8 a, bf16x8 b, f32x4 c) {
  return __builtin_amdgcn_mfma_f32_16x16x32_bf16(a, b, c, 0, 0, 0);
}

// global -> LDS async copy, 16B per lane. LDS dest must be the wave-uniform
// base (HW adds lane*16); global src is per-lane.
__device__ __forceinline__ void gload_lds16(const void* gsrc, void* ldst) {
  auto g = (__attribute__((address_space(1))) void*)(unsigned long long)gsrc;
  auto l = (__attribute__((address_space(3))) void*)(unsigned int)(unsigned long long)ldst;
  __builtin_amdgcn_global_load_lds(g, l, 16, 0, 0);
}

// ---------------- weight transpose + bf16 convert: Wt[n][k] = (bf16)W[k][n]
__global__ __launch_bounds__(256) void transpose_w(
    const float* __restrict__ W0, const float* __restrict__ W1,
    const float* __restrict__ W2, const float* __restrict__ W3,
    bf16_t* __restrict__ T0, bf16_t* __restrict__ T1,
    bf16_t* __restrict__ T2, bf16_t* __restrict__ T3) {
  __shared__ float tile[32][33];
  const float* W = blockIdx.z == 0 ? W0 : blockIdx.z == 1 ? W1 : blockIdx.z == 2 ? W2 : W3;
  bf16_t* Tt = blockIdx.z == 0 ? T0 : blockIdx.z == 1 ? T1 : blockIdx.z == 2 ? T2 : T3;
  const int tx = threadIdx.x & 31, ty = threadIdx.x >> 5;
  const int r0 = blockIdx.y * 32, c0 = blockIdx.x * 32;
#pragma unroll
  for (int i = 0; i < 4; ++i)
    tile[ty + i * 8][tx] = W[(size_t)(r0 + ty + i * 8) * C_SZ + c0 + tx];
  __syncthreads();
#pragma unroll
  for (int i = 0; i < 4; ++i)
    Tt[(size_t)(c0 + ty + i * 8) * C_SZ + r0 + tx] = (bf16_t)tile[tx][ty + i * 8];
}

// ---------------- x fp32 -> bf16
__global__ __launch_bounds__(256) void convert_x(const float* __restrict__ x,
                                                 bf16_t* __restrict__ o) {
  const int idx = blockIdx.x * 256 + threadIdx.x;
  const float4 v = ((const float4*)x)[idx];
  bf16x4 r;
  r[0] = (bf16_t)v.x; r[1] = (bf16_t)v.y; r[2] = (bf16_t)v.z; r[3] = (bf16_t)v.w;
  ((bf16x4*)o)[idx] = r;
}

// ---------------- GEMM: C[M,N] = A[M,K] @ Bt[N,K]^T   (both bf16 row-major)
// 128x128 tile, BK=32, 4 waves (2x2), 16x16x32 MFMA, global_load_lds staging.
template <int OUT_F32>
__global__ __launch_bounds__(256) void gemm_bt(
    const bf16_t* __restrict__ A,
    const bf16_t* __restrict__ Bt0, const bf16_t* __restrict__ Bt1,
    const bf16_t* __restrict__ Bt2,
    void* C0, void* C1, void* C2, int M, int N, int K) {
  __shared__ __align__(16) bf16_t As[128 * 32];
  __shared__ __align__(16) bf16_t Bs[128 * 32];
  const bf16_t* Bt = blockIdx.z == 0 ? Bt0 : blockIdx.z == 1 ? Bt1 : Bt2;
  void* Cv = blockIdx.z == 0 ? C0 : blockIdx.z == 1 ? C1 : C2;
  const int m0 = blockIdx.y * 128, n0 = blockIdx.x * 128;
  const int tid = threadIdx.x;
  const int w = tid >> 6, lane = tid & 63;
  const int wr = w >> 1, wc = w & 1;
  const int g = lane >> 4, l15 = lane & 15;
  const int srow = lane >> 2, ske = (lane & 3) * 8;

  f32x4 acc[4][4] = {};

  for (int k0 = 0; k0 < K; k0 += 32) {
    __syncthreads();
#pragma unroll
    for (int p = 0; p < 2; ++p) {
      const int chunk = p * 4 + w;            // 0..7, wave-uniform
      const int row = chunk * 16 + srow;      // tile row 0..127
      gload_lds16(A + (size_t)(m0 + row) * K + k0 + ske, As + chunk * 512);
      gload_lds16(Bt + (size_t)(n0 + row) * K + k0 + ske, Bs + chunk * 512);
    }
    __syncthreads();
    bf16x8 af[4], bf[4];
#pragma unroll
    for (int r = 0; r < 4; ++r)
      af[r] = *(const bf16x8*)(As + (wr * 64 + r * 16 + l15) * 32 + g * 8);
#pragma unroll
    for (int c = 0; c < 4; ++c)
      bf[c] = *(const bf16x8*)(Bs + (wc * 64 + c * 16 + l15) * 32 + g * 8);
#pragma unroll
    for (int r = 0; r < 4; ++r)
#pragma unroll
      for (int c = 0; c < 4; ++c)
        acc[r][c] = mfma16(af[r], bf[c], acc[r][c]);
  }

#pragma unroll
  for (int r = 0; r < 4; ++r)
#pragma unroll
    for (int c = 0; c < 4; ++c)
#pragma unroll
      for (int i = 0; i < 4; ++i) {
        const size_t idx = (size_t)(m0 + wr * 64 + r * 16 + g * 4 + i) * N +
                           (n0 + wc * 64 + c * 16 + l15);
        if (OUT_F32)
          ((float*)Cv)[idx] = acc[r][c][i];
        else
          ((bf16_t*)Cv)[idx] = (bf16_t)acc[r][c][i];
      }
}

// ---------------- flash sliding-window attention
// grid (T/64, B*H); 4 waves x 16 q-rows; K-tile = 32 keys.
__global__ __launch_bounds__(256) void attn_kernel(
    const bf16_t* __restrict__ Qb, const bf16_t* __restrict__ Kb,
    const bf16_t* __restrict__ Vb, bf16_t* __restrict__ Ob) {
  __shared__ __align__(16) bf16_t Kl[32 * 72];    // [key][d] pad 72
  __shared__ __align__(16) bf16_t VlT[64 * 40];   // [d][key] pad 40
  __shared__ __align__(16) bf16_t Pl[4 * 16 * 32];  // per-wave P scratch

  const int qt = blockIdx.x, bh = blockIdx.y;
  const int b = bh >> 4, h = bh & 15;
  const int q0 = qt * 64;
  const int tid = threadIdx.x, w = tid >> 6, lane = tid & 63;
  const int g = lane >> 4, l15 = lane & 15;
  const int wrow0 = q0 + w * 16;

  // Q fragments for this wave's 16 rows, prescaled by 1/sqrt(64)
  bf16x8 qf[2];
  {
    const bf16_t* qptr = Qb + (size_t)(b * T_SZ + wrow0 + l15) * C_SZ + h * D_SZ;
#pragma unroll
    for (int c2 = 0; c2 < 2; ++c2) {
      bf16x8 t = *(const bf16x8*)(qptr + c2 * 32 + g * 8);
      bf16x8 o;
#pragma unroll
      for (int j = 0; j < 8; ++j) o[j] = (bf16_t)((float)t[j] * 0.125f);
      qf[c2] = o;
    }
  }

  float m_s[4] = {-1e30f, -1e30f, -1e30f, -1e30f};
  float l_s[4] = {0.f, 0.f, 0.f, 0.f};
  f32x4 oacc[4] = {};

  int kstart = q0 - (WIN - 1);
  if (kstart < 0) kstart = 0;
  kstart &= ~31;

  for (int kt = kstart; kt < q0 + 64; kt += 32) {
    __syncthreads();
    {  // stage K tile [32][64] and V^T tile [64][32]
      const int row = tid >> 3, part = tid & 7;
      const size_t so = (size_t)(b * T_SZ + kt + row) * C_SZ + h * D_SZ + part * 8;
      const uint4 kv = *(const uint4*)(Kb + so);
      *(uint4*)(Kl + row * 72 + part * 8) = kv;
      const uint4 vv = *(const uint4*)(Vb + so);
      const bf16_t* vb = (const bf16_t*)&vv;
#pragma unroll
      for (int u = 0; u < 8; ++u) VlT[(part * 8 + u) * 40 + row] = vb[u];
    }
    __syncthreads();

    if (kt <= wrow0 + 15 && kt + 31 >= wrow0 - (WIN - 1)) {
      f32x4 s0 = {}, s1 = {};
#pragma unroll
      for (int c2 = 0; c2 < 2; ++c2) {
        const bf16x8 kf0 = *(const bf16x8*)(Kl + l15 * 72 + c2 * 32 + g * 8);
        const bf16x8 kf1 = *(const bf16x8*)(Kl + (16 + l15) * 72 + c2 * 32 + g * 8);
        s0 = mfma16(qf[c2], kf0, s0);
        s1 = mfma16(qf[c2], kf1, s1);
      }
      float p0[4], p1[4], mx[4];
#pragma unroll
      for (int i = 0; i < 4; ++i) {
        const int row = wrow0 + g * 4 + i;
        const int ca = kt + l15, cb = kt + 16 + l15;
        const float v0 = (ca <= row && ca + WIN > row) ? s0[i] : -1e30f;
        const float v1 = (cb <= row && cb + WIN > row) ? s1[i] : -1e30f;
        p0[i] = v0; p1[i] = v1;
        mx[i] = fmaxf(v0, v1);
      }
#pragma unroll
      for (int st = 1; st < 16; st <<= 1)
#pragma unroll
        for (int i = 0; i < 4; ++i) mx[i] = fmaxf(mx[i], __shfl_xor(mx[i], st, 16));
      float rs[4], sc[4];
#pragma unroll
      for (int i = 0; i < 4; ++i) {
        const float mnew = fmaxf(m_s[i], mx[i]);
        sc[i] = __expf(m_s[i] - mnew);
        m_s[i] = mnew;
        p0[i] = __expf(p0[i] - mnew);
        p1[i] = __expf(p1[i] - mnew);
        rs[i] = p0[i] + p1[i];
      }
#pragma unroll
      for (int st = 1; st < 16; st <<= 1)
#pragma unroll
        for (int i = 0; i < 4; ++i) rs[i] += __shfl_xor(rs[i], st, 16);
#pragma unroll
      for (int i = 0; i < 4; ++i) {
        l_s[i] = l_s[i] * sc[i] + rs[i];
#pragma unroll
        for (int c = 0; c < 4; ++c) oacc[c][i] *= sc[i];
      }
      // P (f32, acc layout) -> bf16 LDS -> A-operand layout
      bf16_t* Plw = Pl + w * 512;
#pragma unroll
      for (int i = 0; i < 4; ++i) {
        Plw[(g * 4 + i) * 32 + l15] = (bf16_t)p0[i];
        Plw[(g * 4 + i) * 32 + 16 + l15] = (bf16_t)p1[i];
      }
      const bf16x8 pa = *(const bf16x8*)(Plw + l15 * 32 + g * 8);
#pragma unroll
      for (int c = 0; c < 4; ++c) {
        const bf16x8 vf = *(const bf16x8*)(VlT + (c * 16 + l15) * 40 + g * 8);
        oacc[c] = mfma16(pa, vf, oacc[c]);
      }
    }
  }

#pragma unroll
  for (int i = 0; i < 4; ++i) {
    const float inv = 1.0f / l_s[i];
    const size_t ro = (size_t)(b * T_SZ + wrow0 + g * 4 + i) * C_SZ + h * D_SZ;
#pragma unroll
    for (int c = 0; c < 4; ++c)
      Ob[ro + c * 16 + l15] = (bf16_t)(oacc[c][i] * inv);
  }
}

extern "C" void kernel_launch(void* const* d_in, const int* in_sizes, int n_in,
                              void* d_out, int out_size, void* d_ws, size_t ws_size,
                              hipStream_t stream) {
  const float* x = (const float*)d_in[0];
  const float* Wq = (const float*)d_in[1];
  const float* Wk = (const float*)d_in[2];
  const float* Wv = (const float*)d_in[3];
  const float* Wo = (const float*)d_in[4];
  float* out = (float*)d_out;
  char* ws = (char*)d_ws;
  const size_t MB = 1ull << 20;
  bf16_t* xb = (bf16_t*)(ws);              // [4096,1024]; reused as attn out
  bf16_t* Qb = (bf16_t*)(ws + 8 * MB);
  bf16_t* Kb = (bf16_t*)(ws + 16 * MB);
  bf16_t* Vb = (bf16_t*)(ws + 24 * MB);
  bf16_t* WqT = (bf16_t*)(ws + 32 * MB);
  bf16_t* WkT = (bf16_t*)(ws + 34 * MB);
  bf16_t* WvT = (bf16_t*)(ws + 36 * MB);
  bf16_t* WoT = (bf16_t*)(ws + 38 * MB);

  transpose_w<<<dim3(32, 32, 4), 256, 0, stream>>>(Wq, Wk, Wv, Wo, WqT, WkT, WvT, WoT);
  convert_x<<<dim3(4096), 256, 0, stream>>>(x, xb);
  gemm_bt<0><<<dim3(8, 32, 3), 256, 0, stream>>>(
      xb, WqT, WkT, WvT, (void*)Qb, (void*)Kb, (void*)Vb, B_SZ * T_SZ, C_SZ, C_SZ);
  attn_kernel<<<dim3(T_SZ / 64, B_SZ * H_CNT), 256, 0, stream>>>(Qb, Kb, Vb, xb);
  gemm_bt<1><<<dim3(8, 32, 1), 256, 0, stream>>>(
      xb, WoT, WoT, WoT, (void*)out, (void*)out, (void*)out, B_SZ * T_SZ, C_SZ, C_SZ);
}

// Round 2
// 117.631 us; speedup vs baseline: 1.2024x; 1.2024x over previous
//
#include <hip/hip_runtime.h>

#define B_SZ 2
#define T_SZ 2048
#define C_SZ 1024
#define H_CNT 16
#define D_SZ 64
#define WIN 512

typedef __bf16 bf16_t;
typedef bf16_t bf16x8 __attribute__((ext_vector_type(8)));
typedef bf16_t bf16x4 __attribute__((ext_vector_type(4)));
typedef float f32x4 __attribute__((ext_vector_type(4)));
typedef unsigned int u32;

__device__ __forceinline__ f32x4 mfma16(bf16x8 a, bf16x8 b, f32x4 c) {
  return __builtin_amdgcn_mfma_f32_16x16x32_bf16(a, b, c, 0, 0, 0);
}

// global -> LDS async copy, 16B per lane. LDS dest is wave-uniform base
// (HW adds lane*16); global src is per-lane (enables source pre-swizzle).
__device__ __forceinline__ void gload_lds16(const void* gsrc, void* ldst) {
  auto g = (__attribute__((address_space(1))) void*)(unsigned long long)gsrc;
  auto l = (__attribute__((address_space(3))) void*)(unsigned int)(unsigned long long)ldst;
  __builtin_amdgcn_global_load_lds(g, l, 16, 0, 0);
}

// ---------------- weight transpose + bf16 convert: Wt[n][k] = (bf16)W[k][n]
__global__ __launch_bounds__(256) void transpose_w(
    const float* __restrict__ W0, const float* __restrict__ W1,
    const float* __restrict__ W2, const float* __restrict__ W3,
    bf16_t* __restrict__ T0, bf16_t* __restrict__ T1,
    bf16_t* __restrict__ T2, bf16_t* __restrict__ T3) {
  __shared__ float tile[32][33];
  const float* W = blockIdx.z == 0 ? W0 : blockIdx.z == 1 ? W1 : blockIdx.z == 2 ? W2 : W3;
  bf16_t* Tt = blockIdx.z == 0 ? T0 : blockIdx.z == 1 ? T1 : blockIdx.z == 2 ? T2 : T3;
  const int tx = threadIdx.x & 31, ty = threadIdx.x >> 5;
  const int r0 = blockIdx.y * 32, c0 = blockIdx.x * 32;
#pragma unroll
  for (int i = 0; i < 4; ++i)
    tile[ty + i * 8][tx] = W[(size_t)(r0 + ty + i * 8) * C_SZ + c0 + tx];
  __syncthreads();
#pragma unroll
  for (int i = 0; i < 4; ++i)
    Tt[(size_t)(c0 + ty + i * 8) * C_SZ + r0 + tx] = (bf16_t)tile[tx][ty + i * 8];
}

// ---------------- x fp32 -> bf16
__global__ __launch_bounds__(256) void convert_x(const float* __restrict__ x,
                                                 bf16_t* __restrict__ o) {
  const int idx = blockIdx.x * 256 + threadIdx.x;
  const float4 v = ((const float4*)x)[idx];
  bf16x4 r;
  r[0] = (bf16_t)v.x; r[1] = (bf16_t)v.y; r[2] = (bf16_t)v.z; r[3] = (bf16_t)v.w;
  ((bf16x4*)o)[idx] = r;
}

// ---------------- V transpose: Vb [B*T][H*D] -> Vt [B*H][D][T]
__global__ __launch_bounds__(256) void transpose_v(const bf16_t* __restrict__ Vb,
                                                   bf16_t* __restrict__ Vt) {
  __shared__ bf16_t tile[32][33];
  const int t0 = blockIdx.x * 32, d0 = blockIdx.y * 32, bh = blockIdx.z;
  const int b = bh >> 4, h = bh & 15;
  const int tx = threadIdx.x & 31, ty = threadIdx.x >> 5;
#pragma unroll
  for (int i = 0; i < 4; ++i)
    tile[ty + i * 8][tx] =
        Vb[((size_t)b * T_SZ + t0 + ty + i * 8) * C_SZ + h * D_SZ + d0 + tx];
  __syncthreads();
#pragma unroll
  for (int i = 0; i < 4; ++i)
    Vt[((size_t)bh * D_SZ + d0 + ty + i * 8) * T_SZ + t0 + tx] = tile[tx][ty + i * 8];
}

// ---------------- GEMM: C[M,N] = A[M,K] @ Bt[N,K]^T   (both bf16 row-major)
template <int OUT_F32>
__global__ __launch_bounds__(256) void gemm_bt(
    const bf16_t* __restrict__ A,
    const bf16_t* __restrict__ Bt0, const bf16_t* __restrict__ Bt1,
    const bf16_t* __restrict__ Bt2,
    void* C0, void* C1, void* C2, int M, int N, int K) {
  __shared__ __align__(16) bf16_t As[128 * 32];
  __shared__ __align__(16) bf16_t Bs[128 * 32];
  const bf16_t* Bt = blockIdx.z == 0 ? Bt0 : blockIdx.z == 1 ? Bt1 : Bt2;
  void* Cv = blockIdx.z == 0 ? C0 : blockIdx.z == 1 ? C1 : C2;
  const int m0 = blockIdx.y * 128, n0 = blockIdx.x * 128;
  const int tid = threadIdx.x;
  const int w = tid >> 6, lane = tid & 63;
  const int wr = w >> 1, wc = w & 1;
  const int g = lane >> 4, l15 = lane & 15;
  const int srow = lane >> 2, ske = (lane & 3) * 8;

  f32x4 acc[4][4] = {};

  for (int k0 = 0; k0 < K; k0 += 32) {
    __syncthreads();
#pragma unroll
    for (int p = 0; p < 2; ++p) {
      const int chunk = p * 4 + w;
      const int row = chunk * 16 + srow;
      gload_lds16(A + (size_t)(m0 + row) * K + k0 + ske, As + chunk * 512);
      gload_lds16(Bt + (size_t)(n0 + row) * K + k0 + ske, Bs + chunk * 512);
    }
    __syncthreads();
    bf16x8 af[4], bf[4];
#pragma unroll
    for (int r = 0; r < 4; ++r)
      af[r] = *(const bf16x8*)(As + (wr * 64 + r * 16 + l15) * 32 + g * 8);
#pragma unroll
    for (int c = 0; c < 4; ++c)
      bf[c] = *(const bf16x8*)(Bs + (wc * 64 + c * 16 + l15) * 32 + g * 8);
#pragma unroll
    for (int r = 0; r < 4; ++r)
#pragma unroll
      for (int c = 0; c < 4; ++c)
        acc[r][c] = mfma16(af[r], bf[c], acc[r][c]);
  }

#pragma unroll
  for (int r = 0; r < 4; ++r)
#pragma unroll
    for (int c = 0; c < 4; ++c)
#pragma unroll
      for (int i = 0; i < 4; ++i) {
        const size_t idx = (size_t)(m0 + wr * 64 + r * 16 + g * 4 + i) * N +
                           (n0 + wc * 64 + c * 16 + l15);
        if (OUT_F32)
          ((float*)Cv)[idx] = acc[r][c][i];
        else
          ((bf16_t*)Cv)[idx] = (bf16_t)acc[r][c][i];
      }
}

// ---------------- flash sliding-window attention, swapped-QK in-register SM
// grid (T/64, B*H); 4 waves x 16 q-rows; K-tile = 64 keys.
// Kl: [key][d] 64x64 bf16, chunk-swizzled (LDS chunk j of row r holds global
// chunk j^(r&7)); Vl: [d][key] same swizzle, staged from pre-transposed Vt.
__global__ __launch_bounds__(256) void attn_kernel(
    const bf16_t* __restrict__ Qb, const bf16_t* __restrict__ Kb,
    const bf16_t* __restrict__ Vt, bf16_t* __restrict__ Ob) {
  __shared__ __align__(16) bf16_t Kl[64 * 64];
  __shared__ __align__(16) bf16_t Vl[64 * 64];

  const int qt = ((blockIdx.x & 7) << 2) | (blockIdx.x >> 3);  // XCD-chunked
  const int bh = blockIdx.y;
  const int b = bh >> 4, h = bh & 15;
  const int q0 = qt * 64;
  const int tid = threadIdx.x, w = tid >> 6, lane = tid & 63;
  const int g = lane >> 4, l15 = lane & 15, gh = g >> 1;
  const int wrow0 = q0 + w * 16;
  const int myrow = wrow0 + l15;
  const int sub = lane >> 3, jj = lane & 7;
  const int sw = l15 & 7;

  // Q fragments (B-operand), prescaled by 1/sqrt(64)*log2(e)
  bf16x8 qf[2];
  {
    const bf16_t* qptr = Qb + ((size_t)b * T_SZ + myrow) * C_SZ + h * D_SZ;
    const float QSC = 0.125f * 1.44269504f;
#pragma unroll
    for (int c2 = 0; c2 < 2; ++c2) {
      bf16x8 t = *(const bf16x8*)(qptr + c2 * 32 + g * 8);
      bf16x8 o;
#pragma unroll
      for (int j = 0; j < 8; ++j) o[j] = (bf16_t)((float)t[j] * QSC);
      qf[c2] = o;
    }
  }

  float m_s = -1e30f, l_s = 0.f;
  f32x4 oacc[4] = {};

  int kstart = q0 - (WIN - 1);
  if (kstart < 0) kstart = 0;
  kstart &= ~63;

  for (int kt = kstart; kt < q0 + 64; kt += 64) {
    __syncthreads();
#pragma unroll
    for (int cc = 0; cc < 2; ++cc) {
      const int chunk = w * 2 + cc;
      const int row = chunk * 8 + sub;
      const int sj = jj ^ sub;  // pre-swizzle source chunk
      gload_lds16(Kb + ((size_t)b * T_SZ + kt + row) * C_SZ + h * D_SZ + sj * 8,
                  Kl + chunk * 512);
      gload_lds16(Vt + ((size_t)bh * D_SZ + row) * T_SZ + kt + sj * 8,
                  Vl + chunk * 512);
    }
    __syncthreads();

    const bool active = (kt <= wrow0 + 15) && (kt + 63 >= wrow0 - (WIN - 1));
    if (!active) continue;

    // QK^T (swapped): s[t] -> S[key = kt+t*16+g*4+i][q = wrow0+l15]
    f32x4 s[4] = {};
#pragma unroll
    for (int t = 0; t < 4; ++t) {
      const bf16_t* kbase = Kl + (t * 16 + l15) * 64;
#pragma unroll
      for (int c2 = 0; c2 < 2; ++c2) {
        const bf16x8 kf = *(const bf16x8*)(kbase + (((c2 * 4 + g) ^ sw) << 3));
        s[t] = mfma16(kf, qf[c2], s[t]);
      }
    }

    const bool interior = (kt + 63 <= wrow0) && (kt >= wrow0 + 15 - (WIN - 1));
    float sv[4][4];
    if (interior) {
#pragma unroll
      for (int t = 0; t < 4; ++t)
#pragma unroll
        for (int i = 0; i < 4; ++i) sv[t][i] = s[t][i];
    } else {
#pragma unroll
      for (int t = 0; t < 4; ++t)
#pragma unroll
        for (int i = 0; i < 4; ++i) {
          const int kk = kt + t * 16 + g * 4 + i;
          sv[t][i] = (kk <= myrow && kk > myrow - WIN) ? s[t][i] : -1e30f;
        }
    }

    // row max: 16 in-reg + 2 cross-group hops (lane owns q-row = l15)
    float mx = sv[0][0];
#pragma unroll
    for (int t = 0; t < 4; ++t)
#pragma unroll
      for (int i = 0; i < 4; ++i)
        if (t || i) mx = fmaxf(mx, sv[t][i]);
    mx = fmaxf(mx, __shfl_xor(mx, 16));
    mx = fmaxf(mx, __shfl_xor(mx, 32));

    const float mnew = fmaxf(m_s, mx);
    const float scl = exp2f(m_s - mnew);
    const float mbase = (mnew > -1e29f) ? mnew : 1e30f;  // fully-masked row -> p=0
    m_s = mnew;

    float p[4][4];
    float rsum = 0.f;
#pragma unroll
    for (int t = 0; t < 4; ++t)
#pragma unroll
      for (int i = 0; i < 4; ++i) {
        p[t][i] = exp2f(sv[t][i] - mbase);
        rsum += p[t][i];
      }
    rsum += __shfl_xor(rsum, 16);
    rsum += __shfl_xor(rsum, 32);
    l_s = l_s * scl + rsum;

    // rescale O (lane owns O rows g*4+i -> broadcast scl from lane g*4+i)
    float sc4[4];
#pragma unroll
    for (int i = 0; i < 4; ++i) sc4[i] = __shfl(scl, g * 4 + i, 16);
#pragma unroll
    for (int c = 0; c < 4; ++c)
#pragma unroll
      for (int i = 0; i < 4; ++i) oacc[c][i] *= sc4[i];

    // pack P rows to bf16 pairs: Wp[t][w2] = keys t*16+g*4+{2w2,2w2+1}
    u32 Wp[4][2];
#pragma unroll
    for (int t = 0; t < 4; ++t)
#pragma unroll
      for (int w2 = 0; w2 < 2; ++w2) {
        union { bf16_t hh[2]; u32 uu; } pk;
        pk.hh[0] = (bf16_t)p[t][2 * w2];
        pk.hh[1] = (bf16_t)p[t][2 * w2 + 1];
        Wp[t][w2] = pk.uu;
      }

    // PV with permuted contraction order sigma (same perm on A and B frags):
    // lane's k-slice j0..3 = own keys (t=2kp+gh, i=0..3);
    // j4..7 = partner lane^32's keys (its t = 2kp+1-gh_src == our tA).
#pragma unroll
    for (int kp = 0; kp < 2; ++kp) {
      const u32 lo0 = Wp[2 * kp][0], lo1 = Wp[2 * kp][1];
      const u32 hi0 = Wp[2 * kp + 1][0], hi1 = Wp[2 * kp + 1][1];
      union { u32 u[4]; bf16x8 v; } pa;
      pa.u[0] = gh ? hi0 : lo0;
      pa.u[1] = gh ? hi1 : lo1;
      pa.u[2] = (u32)__shfl_xor((int)(gh ? lo0 : hi0), 32);
      pa.u[3] = (u32)__shfl_xor((int)(gh ? lo1 : hi1), 32);

      const int tA = 2 * kp + gh;
      const int low = (g & 1) * 4;
      const int cA = ((tA * 2 + gh) ^ sw) << 3;        // swizzled chunk of colA
      const int cB = ((tA * 2 + (gh ^ 1)) ^ sw) << 3;  // swizzled chunk of colB
#pragma unroll
      for (int c = 0; c < 4; ++c) {
        const bf16_t* vbase = Vl + (c * 16 + l15) * 64;
        union { bf16x4 h[2]; bf16x8 v; } vv;
        vv.h[0] = *(const bf16x4*)(vbase + cA + low);
        vv.h[1] = *(const bf16x4*)(vbase + cB + low);
        oacc[c] = mfma16(pa.v, vv.v, oacc[c]);
      }
    }
  }

  // epilogue: normalize + store (lane writes O rows g*4+i, col c*16+l15)
  const float invl = 1.0f / l_s;
  float inv4[4];
#pragma unroll
  for (int i = 0; i < 4; ++i) inv4[i] = __shfl(invl, g * 4 + i, 16);
#pragma unroll
  for (int i = 0; i < 4; ++i) {
    const size_t ro = ((size_t)b * T_SZ + wrow0 + g * 4 + i) * C_SZ + h * D_SZ;
#pragma unroll
    for (int c = 0; c < 4; ++c)
      Ob[ro + c * 16 + l15] = (bf16_t)(oacc[c][i] * inv4[i]);
  }
}

extern "C" void kernel_launch(void* const* d_in, const int* in_sizes, int n_in,
                              void* d_out, int out_size, void* d_ws, size_t ws_size,
                              hipStream_t stream) {
  const float* x = (const float*)d_in[0];
  const float* Wq = (const float*)d_in[1];
  const float* Wk = (const float*)d_in[2];
  const float* Wv = (const float*)d_in[3];
  const float* Wo = (const float*)d_in[4];
  float* out = (float*)d_out;
  char* ws = (char*)d_ws;
  const size_t MB = 1ull << 20;
  bf16_t* xb = (bf16_t*)(ws);               // [4096,1024]; becomes Vt after QKV gemm
  bf16_t* Vtp = (bf16_t*)(ws);              // Vt [32][64][2048] overlays xb
  bf16_t* Qb = (bf16_t*)(ws + 8 * MB);
  bf16_t* Kb = (bf16_t*)(ws + 16 * MB);
  bf16_t* Vb = (bf16_t*)(ws + 24 * MB);     // raw V; later reused as attn out
  bf16_t* aOut = (bf16_t*)(ws + 24 * MB);
  bf16_t* WqT = (bf16_t*)(ws + 32 * MB);
  bf16_t* WkT = (bf16_t*)(ws + 34 * MB);
  bf16_t* WvT = (bf16_t*)(ws + 36 * MB);
  bf16_t* WoT = (bf16_t*)(ws + 38 * MB);

  transpose_w<<<dim3(32, 32, 4), 256, 0, stream>>>(Wq, Wk, Wv, Wo, WqT, WkT, WvT, WoT);
  convert_x<<<dim3(4096), 256, 0, stream>>>(x, xb);
  gemm_bt<0><<<dim3(8, 32, 3), 256, 0, stream>>>(
      xb, WqT, WkT, WvT, (void*)Qb, (void*)Kb, (void*)Vb, B_SZ * T_SZ, C_SZ, C_SZ);
  transpose_v<<<dim3(64, 2, 32), 256, 0, stream>>>(Vb, Vtp);  // clobbers xb (done)
  attn_kernel<<<dim3(T_SZ / 64, B_SZ * H_CNT), 256, 0, stream>>>(Qb, Kb, Vtp, aOut);
  gemm_bt<1><<<dim3(8, 32, 1), 256, 0, stream>>>(
      aOut, WoT, WoT, WoT, (void*)out, (void*)out, (void*)out, B_SZ * T_SZ, C_SZ, C_SZ);
}

// Round 3
// 113.643 us; speedup vs baseline: 1.2445x; 1.0351x over previous
//
#include <hip/hip_runtime.h>

#define B_SZ 2
#define T_SZ 2048
#define C_SZ 1024
#define K_SZ 1024
#define QKV_LD 3072
#define H_CNT 16
#define D_SZ 64
#define WIN 512

typedef __bf16 bf16_t;
typedef bf16_t bf16x8 __attribute__((ext_vector_type(8)));
typedef bf16_t bf16x4 __attribute__((ext_vector_type(4)));
typedef float f32x4 __attribute__((ext_vector_type(4)));
typedef unsigned int u32;

__device__ __forceinline__ f32x4 mfma16(bf16x8 a, bf16x8 b, f32x4 c) {
  return __builtin_amdgcn_mfma_f32_16x16x32_bf16(a, b, c, 0, 0, 0);
}

__device__ __forceinline__ void gload_lds16(const void* gsrc, void* ldst) {
  auto g = (__attribute__((address_space(1))) void*)(unsigned long long)gsrc;
  auto l = (__attribute__((address_space(3))) void*)(unsigned int)(unsigned long long)ldst;
  __builtin_amdgcn_global_load_lds(g, l, 16, 0, 0);
}

// ---------------- weight transpose + bf16 convert: Wt[n][k] = (bf16)W[k][n]
__global__ __launch_bounds__(256) void transpose_w(
    const float* __restrict__ W0, const float* __restrict__ W1,
    const float* __restrict__ W2, const float* __restrict__ W3,
    bf16_t* __restrict__ T0, bf16_t* __restrict__ T1,
    bf16_t* __restrict__ T2, bf16_t* __restrict__ T3) {
  __shared__ float tile[32][33];
  const float* W = blockIdx.z == 0 ? W0 : blockIdx.z == 1 ? W1 : blockIdx.z == 2 ? W2 : W3;
  bf16_t* Tt = blockIdx.z == 0 ? T0 : blockIdx.z == 1 ? T1 : blockIdx.z == 2 ? T2 : T3;
  const int tx = threadIdx.x & 31, ty = threadIdx.x >> 5;
  const int r0 = blockIdx.y * 32, c0 = blockIdx.x * 32;
#pragma unroll
  for (int i = 0; i < 4; ++i)
    tile[ty + i * 8][tx] = W[(size_t)(r0 + ty + i * 8) * C_SZ + c0 + tx];
  __syncthreads();
#pragma unroll
  for (int i = 0; i < 4; ++i)
    Tt[(size_t)(c0 + ty + i * 8) * C_SZ + r0 + tx] = (bf16_t)tile[tx][ty + i * 8];
}

// ---------------- x fp32 -> bf16
__global__ __launch_bounds__(256) void convert_x(const float* __restrict__ x,
                                                 bf16_t* __restrict__ o) {
  const int idx = blockIdx.x * 256 + threadIdx.x;
  const float4 v = ((const float4*)x)[idx];
  bf16x4 r;
  r[0] = (bf16_t)v.x; r[1] = (bf16_t)v.y; r[2] = (bf16_t)v.z; r[3] = (bf16_t)v.w;
  ((bf16x4*)o)[idx] = r;
}

// ---------------- V transpose: QKV V-cols -> Vt [B*H][D][T]
__global__ __launch_bounds__(256) void transpose_v(const bf16_t* __restrict__ QKV,
                                                   bf16_t* __restrict__ Vt) {
  __shared__ bf16_t tile[32][33];
  const int t0 = blockIdx.x * 32, d0 = blockIdx.y * 32, bh = blockIdx.z;
  const int b = bh >> 4, h = bh & 15;
  const int tx = threadIdx.x & 31, ty = threadIdx.x >> 5;
#pragma unroll
  for (int i = 0; i < 4; ++i)
    tile[ty + i * 8][tx] =
        QKV[((size_t)b * T_SZ + t0 + ty + i * 8) * QKV_LD + 2048 + h * D_SZ + d0 + tx];
  __syncthreads();
#pragma unroll
  for (int i = 0; i < 4; ++i)
    Vt[((size_t)bh * D_SZ + d0 + ty + i * 8) * T_SZ + t0 + tx] = tile[tx][ty + i * 8];
}

// ---------------- 256x256 8-phase GEMM: C[M,N] = A[M,K] @ Bt[N,K]^T
// M=4096, N=3072, K=1024. 8 waves (2Mx4N), BK=64, 128KB dbuf LDS,
// XOR chunk-swizzle both sides, raw barriers, per-tile vmcnt(0), setprio.
#define GM_NT 16  // K / 64

__global__ __launch_bounds__(512, 2) void gemm256(
    const bf16_t* __restrict__ A, const bf16_t* __restrict__ Bt,
    bf16_t* __restrict__ C) {
  __shared__ __align__(16) bf16_t As[2][256 * 64];
  __shared__ __align__(16) bf16_t Bs[2][256 * 64];
  const int m0 = blockIdx.y * 256, n0 = blockIdx.x * 256;
  const int tid = threadIdx.x, w = tid >> 6, lane = tid & 63;
  const int wr = w >> 2, wc = w & 3;
  const int g = lane >> 4, l15 = lane & 15, sw = l15 & 7;
  const int srow = lane >> 3, sj = lane & 7;

  f32x4 acc[8][4] = {};

  // stage one 128-row half (rows half*128..+127, 64 cols) of a K-tile
  auto stageA = [&](int buf, int half, int k0) {
#pragma unroll
    for (int q8 = 0; q8 < 2; ++q8) {
      const int rg = w * 16 + q8 * 8;
      gload_lds16(A + (size_t)(m0 + half * 128 + rg + srow) * K_SZ + k0 + ((sj ^ srow) << 3),
                  &As[buf][half * 8192 + rg * 64]);
    }
  };
  auto stageB = [&](int buf, int half, int k0) {
#pragma unroll
    for (int q8 = 0; q8 < 2; ++q8) {
      const int rg = w * 16 + q8 * 8;
      gload_lds16(Bt + (size_t)(n0 + half * 128 + rg + srow) * K_SZ + k0 + ((sj ^ srow) << 3),
                  &Bs[buf][half * 8192 + rg * 64]);
    }
  };

  // prologue: stage tile 0 into buf 0
  stageA(0, 0, 0); stageA(0, 1, 0); stageB(0, 0, 0); stageB(0, 1, 0);

#define LDAF(MF4, MH, KK) \
  (*(const bf16x8*)&As[buf][(wr * 128 + ((MH) * 4 + (MF4)) * 16 + l15) * 64 + \
                            ((((KK) << 2) | g) ^ sw) * 8])
#define LDBF(NF, KK) \
  (*(const bf16x8*)&Bs[buf][(wc * 64 + (NF) * 16 + l15) * 64 + \
                            ((((KK) << 2) | g) ^ sw) * 8])
#define MROW(MH, MF, AF)                                   \
  acc[(MH) * 4 + (MF)][0] = mfma16(AF, bf0, acc[(MH) * 4 + (MF)][0]); \
  acc[(MH) * 4 + (MF)][1] = mfma16(AF, bf1, acc[(MH) * 4 + (MF)][1]); \
  acc[(MH) * 4 + (MF)][2] = mfma16(AF, bf2, acc[(MH) * 4 + (MF)][2]); \
  acc[(MH) * 4 + (MF)][3] = mfma16(AF, bf3, acc[(MH) * 4 + (MF)][3]);

#pragma unroll 2
  for (int t = 0; t < GM_NT; ++t) {
    const int buf = t & 1, nb = buf ^ 1;
    const int k1 = (t + 1) * 64;
    // tile entry: all waves' staged loads for buf have landed
    asm volatile("s_waitcnt vmcnt(0)" ::: "memory");
    __builtin_amdgcn_s_barrier();

    bf16x8 bf0, bf1, bf2, bf3;
    {  // P0: (mh0, kk0) + stage A halves of t+1
      bf16x8 a0 = LDAF(0, 0, 0), a1 = LDAF(1, 0, 0), a2 = LDAF(2, 0, 0), a3 = LDAF(3, 0, 0);
      bf0 = LDBF(0, 0); bf1 = LDBF(1, 0); bf2 = LDBF(2, 0); bf3 = LDBF(3, 0);
      if (t < GM_NT - 1) { stageA(nb, 0, k1); stageA(nb, 1, k1); }
      __builtin_amdgcn_s_barrier();
      __builtin_amdgcn_s_setprio(1);
      MROW(0, 0, a0) MROW(0, 1, a1) MROW(0, 2, a2) MROW(0, 3, a3)
      __builtin_amdgcn_s_setprio(0);
      __builtin_amdgcn_s_barrier();
    }
    {  // P1: (mh1, kk0) + stage B halves of t+1
      bf16x8 a0 = LDAF(0, 1, 0), a1 = LDAF(1, 1, 0), a2 = LDAF(2, 1, 0), a3 = LDAF(3, 1, 0);
      if (t < GM_NT - 1) { stageB(nb, 0, k1); stageB(nb, 1, k1); }
      __builtin_amdgcn_s_barrier();
      __builtin_amdgcn_s_setprio(1);
      MROW(1, 0, a0) MROW(1, 1, a1) MROW(1, 2, a2) MROW(1, 3, a3)
      __builtin_amdgcn_s_setprio(0);
      __builtin_amdgcn_s_barrier();
    }
    {  // P2: (mh0, kk1)
      bf16x8 a0 = LDAF(0, 0, 1), a1 = LDAF(1, 0, 1), a2 = LDAF(2, 0, 1), a3 = LDAF(3, 0, 1);
      bf0 = LDBF(0, 1); bf1 = LDBF(1, 1); bf2 = LDBF(2, 1); bf3 = LDBF(3, 1);
      __builtin_amdgcn_s_barrier();
      __builtin_amdgcn_s_setprio(1);
      MROW(0, 0, a0) MROW(0, 1, a1) MROW(0, 2, a2) MROW(0, 3, a3)
      __builtin_amdgcn_s_setprio(0);
      __builtin_amdgcn_s_barrier();
    }
    {  // P3: (mh1, kk1)
      bf16x8 a0 = LDAF(0, 1, 1), a1 = LDAF(1, 1, 1), a2 = LDAF(2, 1, 1), a3 = LDAF(3, 1, 1);
      __builtin_amdgcn_s_barrier();
      __builtin_amdgcn_s_setprio(1);
      MROW(1, 0, a0) MROW(1, 1, a1) MROW(1, 2, a2) MROW(1, 3, a3)
      __builtin_amdgcn_s_setprio(0);
      // tile-end barrier is the next iteration's entry barrier
    }
  }

#pragma unroll
  for (int mf = 0; mf < 8; ++mf)
#pragma unroll
    for (int nf = 0; nf < 4; ++nf)
#pragma unroll
      for (int i = 0; i < 4; ++i)
        C[(size_t)(m0 + wr * 128 + mf * 16 + g * 4 + i) * QKV_LD +
          n0 + wc * 64 + nf * 16 + l15] = (bf16_t)acc[mf][nf][i];
}

// ---------------- 128x128 GEMM (m97 structure) for the Wo projection, f32 out
__global__ __launch_bounds__(256) void gemm_bt(
    const bf16_t* __restrict__ A, int lda, const bf16_t* __restrict__ Bt,
    float* __restrict__ C, int M, int N, int K) {
  __shared__ __align__(16) bf16_t As[128 * 32];
  __shared__ __align__(16) bf16_t Bs[128 * 32];
  const int m0 = blockIdx.y * 128, n0 = blockIdx.x * 128;
  const int tid = threadIdx.x;
  const int w = tid >> 6, lane = tid & 63;
  const int wr = w >> 1, wc = w & 1;
  const int g = lane >> 4, l15 = lane & 15;
  const int srow = lane >> 2, ske = (lane & 3) * 8;

  f32x4 acc[4][4] = {};

  for (int k0 = 0; k0 < K; k0 += 32) {
    __syncthreads();
#pragma unroll
    for (int p = 0; p < 2; ++p) {
      const int chunk = p * 4 + w;
      const int row = chunk * 16 + srow;
      gload_lds16(A + (size_t)(m0 + row) * lda + k0 + ske, As + chunk * 512);
      gload_lds16(Bt + (size_t)(n0 + row) * K + k0 + ske, Bs + chunk * 512);
    }
    __syncthreads();
    bf16x8 af[4], bfr[4];
#pragma unroll
    for (int r = 0; r < 4; ++r)
      af[r] = *(const bf16x8*)(As + (wr * 64 + r * 16 + l15) * 32 + g * 8);
#pragma unroll
    for (int c = 0; c < 4; ++c)
      bfr[c] = *(const bf16x8*)(Bs + (wc * 64 + c * 16 + l15) * 32 + g * 8);
#pragma unroll
    for (int r = 0; r < 4; ++r)
#pragma unroll
      for (int c = 0; c < 4; ++c)
        acc[r][c] = mfma16(af[r], bfr[c], acc[r][c]);
  }

#pragma unroll
  for (int r = 0; r < 4; ++r)
#pragma unroll
    for (int c = 0; c < 4; ++c)
#pragma unroll
      for (int i = 0; i < 4; ++i)
        C[(size_t)(m0 + wr * 64 + r * 16 + g * 4 + i) * N +
          n0 + wc * 64 + c * 16 + l15] = acc[r][c][i];
}

// ---------------- flash sliding-window attention (round-2 core, QKV strides)
__global__ __launch_bounds__(256) void attn_kernel(
    bf16_t* __restrict__ QKV, const bf16_t* __restrict__ Vt) {
  __shared__ __align__(16) bf16_t Kl[64 * 64];
  __shared__ __align__(16) bf16_t Vl[64 * 64];

  const int qt = ((blockIdx.x & 7) << 2) | (blockIdx.x >> 3);
  const int bh = blockIdx.y;
  const int b = bh >> 4, h = bh & 15;
  const int q0 = qt * 64;
  const int tid = threadIdx.x, w = tid >> 6, lane = tid & 63;
  const int g = lane >> 4, l15 = lane & 15, gh = g >> 1;
  const int wrow0 = q0 + w * 16;
  const int myrow = wrow0 + l15;
  const int sub = lane >> 3, jj = lane & 7;
  const int sw = l15 & 7;

  bf16x8 qf[2];
  {
    const bf16_t* qptr = QKV + ((size_t)b * T_SZ + myrow) * QKV_LD + h * D_SZ;
    const float QSC = 0.125f * 1.44269504f;
#pragma unroll
    for (int c2 = 0; c2 < 2; ++c2) {
      bf16x8 t = *(const bf16x8*)(qptr + c2 * 32 + g * 8);
      bf16x8 o;
#pragma unroll
      for (int j = 0; j < 8; ++j) o[j] = (bf16_t)((float)t[j] * QSC);
      qf[c2] = o;
    }
  }

  float m_s = -1e30f, l_s = 0.f;
  f32x4 oacc[4] = {};

  int kstart = q0 - (WIN - 1);
  if (kstart < 0) kstart = 0;
  kstart &= ~63;

  for (int kt = kstart; kt < q0 + 64; kt += 64) {
    __syncthreads();
#pragma unroll
    for (int cc = 0; cc < 2; ++cc) {
      const int chunk = w * 2 + cc;
      const int row = chunk * 8 + sub;
      const int sj = jj ^ sub;
      gload_lds16(QKV + ((size_t)b * T_SZ + kt + row) * QKV_LD + 1024 + h * D_SZ + sj * 8,
                  Kl + chunk * 512);
      gload_lds16(Vt + ((size_t)bh * D_SZ + row) * T_SZ + kt + sj * 8,
                  Vl + chunk * 512);
    }
    __syncthreads();

    const bool active = (kt <= wrow0 + 15) && (kt + 63 >= wrow0 - (WIN - 1));
    if (!active) continue;

    f32x4 s[4] = {};
#pragma unroll
    for (int t = 0; t < 4; ++t) {
      const bf16_t* kbase = Kl + (t * 16 + l15) * 64;
#pragma unroll
      for (int c2 = 0; c2 < 2; ++c2) {
        const bf16x8 kf = *(const bf16x8*)(kbase + (((c2 * 4 + g) ^ sw) << 3));
        s[t] = mfma16(kf, qf[c2], s[t]);
      }
    }

    const bool interior = (kt + 63 <= wrow0) && (kt >= wrow0 + 15 - (WIN - 1));
    float sv[4][4];
    if (interior) {
#pragma unroll
      for (int t = 0; t < 4; ++t)
#pragma unroll
        for (int i = 0; i < 4; ++i) sv[t][i] = s[t][i];
    } else {
#pragma unroll
      for (int t = 0; t < 4; ++t)
#pragma unroll
        for (int i = 0; i < 4; ++i) {
          const int kk = kt + t * 16 + g * 4 + i;
          sv[t][i] = (kk <= myrow && kk > myrow - WIN) ? s[t][i] : -1e30f;
        }
    }

    float mx = sv[0][0];
#pragma unroll
    for (int t = 0; t < 4; ++t)
#pragma unroll
      for (int i = 0; i < 4; ++i)
        if (t || i) mx = fmaxf(mx, sv[t][i]);
    mx = fmaxf(mx, __shfl_xor(mx, 16));
    mx = fmaxf(mx, __shfl_xor(mx, 32));

    const float mnew = fmaxf(m_s, mx);
    const float scl = exp2f(m_s - mnew);
    const float mbase = (mnew > -1e29f) ? mnew : 1e30f;
    m_s = mnew;

    float p[4][4];
    float rsum = 0.f;
#pragma unroll
    for (int t = 0; t < 4; ++t)
#pragma unroll
      for (int i = 0; i < 4; ++i) {
        p[t][i] = exp2f(sv[t][i] - mbase);
        rsum += p[t][i];
      }
    rsum += __shfl_xor(rsum, 16);
    rsum += __shfl_xor(rsum, 32);
    l_s = l_s * scl + rsum;

    float sc4[4];
#pragma unroll
    for (int i = 0; i < 4; ++i) sc4[i] = __shfl(scl, g * 4 + i, 16);
#pragma unroll
    for (int c = 0; c < 4; ++c)
#pragma unroll
      for (int i = 0; i < 4; ++i) oacc[c][i] *= sc4[i];

    u32 Wp[4][2];
#pragma unroll
    for (int t = 0; t < 4; ++t)
#pragma unroll
      for (int w2 = 0; w2 < 2; ++w2) {
        union { bf16_t hh[2]; u32 uu; } pk;
        pk.hh[0] = (bf16_t)p[t][2 * w2];
        pk.hh[1] = (bf16_t)p[t][2 * w2 + 1];
        Wp[t][w2] = pk.uu;
      }

#pragma unroll
    for (int kp = 0; kp < 2; ++kp) {
      const u32 lo0 = Wp[2 * kp][0], lo1 = Wp[2 * kp][1];
      const u32 hi0 = Wp[2 * kp + 1][0], hi1 = Wp[2 * kp + 1][1];
      union { u32 u[4]; bf16x8 v; } pa;
      pa.u[0] = gh ? hi0 : lo0;
      pa.u[1] = gh ? hi1 : lo1;
      pa.u[2] = (u32)__shfl_xor((int)(gh ? lo0 : hi0), 32);
      pa.u[3] = (u32)__shfl_xor((int)(gh ? lo1 : hi1), 32);

      const int tA = 2 * kp + gh;
      const int low = (g & 1) * 4;
      const int cA = ((tA * 2 + gh) ^ sw) << 3;
      const int cB = ((tA * 2 + (gh ^ 1)) ^ sw) << 3;
#pragma unroll
      for (int c = 0; c < 4; ++c) {
        const bf16_t* vbase = Vl + (c * 16 + l15) * 64;
        union { bf16x4 h[2]; bf16x8 v; } vv;
        vv.h[0] = *(const bf16x4*)(vbase + cA + low);
        vv.h[1] = *(const bf16x4*)(vbase + cB + low);
        oacc[c] = mfma16(pa.v, vv.v, oacc[c]);
      }
    }
  }

  const float invl = 1.0f / l_s;
  float inv4[4];
#pragma unroll
  for (int i = 0; i < 4; ++i) inv4[i] = __shfl(invl, g * 4 + i, 16);
#pragma unroll
  for (int i = 0; i < 4; ++i) {
    const size_t ro = ((size_t)b * T_SZ + wrow0 + g * 4 + i) * QKV_LD + 2048 + h * D_SZ;
#pragma unroll
    for (int c = 0; c < 4; ++c)
      QKV[ro + c * 16 + l15] = (bf16_t)(oacc[c][i] * inv4[i]);
  }
}

extern "C" void kernel_launch(void* const* d_in, const int* in_sizes, int n_in,
                              void* d_out, int out_size, void* d_ws, size_t ws_size,
                              hipStream_t stream) {
  const float* x = (const float*)d_in[0];
  const float* Wq = (const float*)d_in[1];
  const float* Wk = (const float*)d_in[2];
  const float* Wv = (const float*)d_in[3];
  const float* Wo = (const float*)d_in[4];
  float* out = (float*)d_out;
  char* ws = (char*)d_ws;
  const size_t MB = 1ull << 20;
  bf16_t* xb = (bf16_t*)(ws);                // [4096][1024]; becomes Vt after QKV gemm
  bf16_t* Vtp = (bf16_t*)(ws);               // Vt [32][64][2048] overlays xb
  bf16_t* QKVb = (bf16_t*)(ws + 8 * MB);     // [4096][3072]; V-cols become attn out
  bf16_t* WqT = (bf16_t*)(ws + 32 * MB);     // [3072][1024] combined (q|k|v)
  bf16_t* WkT = (bf16_t*)(ws + 34 * MB);
  bf16_t* WvT = (bf16_t*)(ws + 36 * MB);
  bf16_t* WoT = (bf16_t*)(ws + 38 * MB);

  transpose_w<<<dim3(32, 32, 4), 256, 0, stream>>>(Wq, Wk, Wv, Wo, WqT, WkT, WvT, WoT);
  convert_x<<<dim3(4096), 256, 0, stream>>>(x, xb);
  gemm256<<<dim3(12, 16), 512, 0, stream>>>(xb, WqT, QKVb);
  transpose_v<<<dim3(64, 2, 32), 256, 0, stream>>>(QKVb, Vtp);  // clobbers xb (done)
  attn_kernel<<<dim3(T_SZ / 64, B_SZ * H_CNT), 256, 0, stream>>>(QKVb, Vtp);
  gemm_bt<<<dim3(8, 32), 256, 0, stream>>>(QKVb + 2048, QKV_LD, WoT, out,
                                           B_SZ * T_SZ, C_SZ, C_SZ);
}

// Round 4
// 109.902 us; speedup vs baseline: 1.2869x; 1.0340x over previous
//
#include <hip/hip_runtime.h>

#define B_SZ 2
#define T_SZ 2048
#define C_SZ 1024
#define K_SZ 1024
#define QKV_LD 3072
#define H_CNT 16
#define D_SZ 64
#define WIN 512

typedef __bf16 bf16_t;
typedef bf16_t bf16x8 __attribute__((ext_vector_type(8)));
typedef bf16_t bf16x4 __attribute__((ext_vector_type(4)));
typedef float f32x4 __attribute__((ext_vector_type(4)));
typedef unsigned int u32;

__device__ __forceinline__ f32x4 mfma16(bf16x8 a, bf16x8 b, f32x4 c) {
  return __builtin_amdgcn_mfma_f32_16x16x32_bf16(a, b, c, 0, 0, 0);
}

__device__ __forceinline__ void gload_lds16(const void* gsrc, void* ldst) {
  auto g = (__attribute__((address_space(1))) void*)(unsigned long long)gsrc;
  auto l = (__attribute__((address_space(3))) void*)(unsigned int)(unsigned long long)ldst;
  __builtin_amdgcn_global_load_lds(g, l, 16, 0, 0);
}

// ---------------- prep: weight transpose+convert (z<4) | x convert (z==4)
__global__ __launch_bounds__(256) void prep(
    const float* __restrict__ x, bf16_t* __restrict__ xb,
    const float* __restrict__ W0, const float* __restrict__ W1,
    const float* __restrict__ W2, const float* __restrict__ W3,
    bf16_t* __restrict__ T0, bf16_t* __restrict__ T1,
    bf16_t* __restrict__ T2, bf16_t* __restrict__ T3) {
  if (blockIdx.z == 4) {  // x fp32 -> bf16: 1024 blocks x 256 thr x 4 float4
    const int base = (blockIdx.y * 32 + blockIdx.x) * 256 + threadIdx.x;
#pragma unroll
    for (int j = 0; j < 4; ++j) {
      const int idx = base + j * 262144;
      const float4 v = ((const float4*)x)[idx];
      bf16x4 r;
      r[0] = (bf16_t)v.x; r[1] = (bf16_t)v.y; r[2] = (bf16_t)v.z; r[3] = (bf16_t)v.w;
      ((bf16x4*)xb)[idx] = r;
    }
    return;
  }
  __shared__ float tile[32][33];
  const float* W = blockIdx.z == 0 ? W0 : blockIdx.z == 1 ? W1 : blockIdx.z == 2 ? W2 : W3;
  bf16_t* Tt = blockIdx.z == 0 ? T0 : blockIdx.z == 1 ? T1 : blockIdx.z == 2 ? T2 : T3;
  const int tx = threadIdx.x & 31, ty = threadIdx.x >> 5;
  const int r0 = blockIdx.y * 32, c0 = blockIdx.x * 32;
#pragma unroll
  for (int i = 0; i < 4; ++i)
    tile[ty + i * 8][tx] = W[(size_t)(r0 + ty + i * 8) * C_SZ + c0 + tx];
  __syncthreads();
#pragma unroll
  for (int i = 0; i < 4; ++i)
    Tt[(size_t)(c0 + ty + i * 8) * C_SZ + r0 + tx] = (bf16_t)tile[tx][ty + i * 8];
}

// ---------------- V transpose: QKV V-cols -> Vt [B*H][D][T]
__global__ __launch_bounds__(256) void transpose_v(const bf16_t* __restrict__ QKV,
                                                   bf16_t* __restrict__ Vt) {
  __shared__ bf16_t tile[32][33];
  const int t0 = blockIdx.x * 32, d0 = blockIdx.y * 32, bh = blockIdx.z;
  const int b = bh >> 4, h = bh & 15;
  const int tx = threadIdx.x & 31, ty = threadIdx.x >> 5;
#pragma unroll
  for (int i = 0; i < 4; ++i)
    tile[ty + i * 8][tx] =
        QKV[((size_t)b * T_SZ + t0 + ty + i * 8) * QKV_LD + 2048 + h * D_SZ + d0 + tx];
  __syncthreads();
#pragma unroll
  for (int i = 0; i < 4; ++i)
    Vt[((size_t)bh * D_SZ + d0 + ty + i * 8) * T_SZ + t0 + tx] = tile[tx][ty + i * 8];
}

// ---------------- 256x256 8-phase GEMM: C[M,N] = A[M,K] @ Bt[N,K]^T
#define GM_NT 16  // K / 64

__global__ __launch_bounds__(512, 2) void gemm256(
    const bf16_t* __restrict__ A, const bf16_t* __restrict__ Bt,
    bf16_t* __restrict__ C) {
  __shared__ __align__(16) bf16_t As[2][256 * 64];
  __shared__ __align__(16) bf16_t Bs[2][256 * 64];
  // T1: XCD-contiguous chunks (192 blocks, 24/XCD = 2 M-rows x 12 N-cols)
  const int wg = blockIdx.x + 12 * blockIdx.y;
  const int swz = (wg & 7) * 24 + (wg >> 3);
  const int bx = swz % 12, by = swz / 12;
  const int m0 = by * 256, n0 = bx * 256;
  const int tid = threadIdx.x, w = tid >> 6, lane = tid & 63;
  const int wr = w >> 2, wc = w & 3;
  const int g = lane >> 4, l15 = lane & 15, sw = l15 & 7;
  const int srow = lane >> 3, sj = lane & 7;

  f32x4 acc[8][4] = {};

  auto stageA = [&](int buf, int half, int k0) {
#pragma unroll
    for (int q8 = 0; q8 < 2; ++q8) {
      const int rg = w * 16 + q8 * 8;
      gload_lds16(A + (size_t)(m0 + half * 128 + rg + srow) * K_SZ + k0 + ((sj ^ srow) << 3),
                  &As[buf][half * 8192 + rg * 64]);
    }
  };
  auto stageB = [&](int buf, int half, int k0) {
#pragma unroll
    for (int q8 = 0; q8 < 2; ++q8) {
      const int rg = w * 16 + q8 * 8;
      gload_lds16(Bt + (size_t)(n0 + half * 128 + rg + srow) * K_SZ + k0 + ((sj ^ srow) << 3),
                  &Bs[buf][half * 8192 + rg * 64]);
    }
  };

  stageA(0, 0, 0); stageA(0, 1, 0); stageB(0, 0, 0); stageB(0, 1, 0);

#define LDAF(MF4, MH, KK) \
  (*(const bf16x8*)&As[buf][(wr * 128 + ((MH) * 4 + (MF4)) * 16 + l15) * 64 + \
                            ((((KK) << 2) | g) ^ sw) * 8])
#define LDBF(NF, KK) \
  (*(const bf16x8*)&Bs[buf][(wc * 64 + (NF) * 16 + l15) * 64 + \
                            ((((KK) << 2) | g) ^ sw) * 8])
#define MROW(MH, MF, AF)                                   \
  acc[(MH) * 4 + (MF)][0] = mfma16(AF, bf0, acc[(MH) * 4 + (MF)][0]); \
  acc[(MH) * 4 + (MF)][1] = mfma16(AF, bf1, acc[(MH) * 4 + (MF)][1]); \
  acc[(MH) * 4 + (MF)][2] = mfma16(AF, bf2, acc[(MH) * 4 + (MF)][2]); \
  acc[(MH) * 4 + (MF)][3] = mfma16(AF, bf3, acc[(MH) * 4 + (MF)][3]);

#pragma unroll 2
  for (int t = 0; t < GM_NT; ++t) {
    const int buf = t & 1, nb = buf ^ 1;
    const int k1 = (t + 1) * 64;
    asm volatile("s_waitcnt vmcnt(0)" ::: "memory");
    __builtin_amdgcn_s_barrier();

    bf16x8 bf0, bf1, bf2, bf3;
    {  // P0
      bf16x8 a0 = LDAF(0, 0, 0), a1 = LDAF(1, 0, 0), a2 = LDAF(2, 0, 0), a3 = LDAF(3, 0, 0);
      bf0 = LDBF(0, 0); bf1 = LDBF(1, 0); bf2 = LDBF(2, 0); bf3 = LDBF(3, 0);
      if (t < GM_NT - 1) { stageA(nb, 0, k1); stageA(nb, 1, k1); }
      __builtin_amdgcn_s_barrier();
      __builtin_amdgcn_s_setprio(1);
      MROW(0, 0, a0) MROW(0, 1, a1) MROW(0, 2, a2) MROW(0, 3, a3)
      __builtin_amdgcn_s_setprio(0);
      __builtin_amdgcn_s_barrier();
    }
    {  // P1
      bf16x8 a0 = LDAF(0, 1, 0), a1 = LDAF(1, 1, 0), a2 = LDAF(2, 1, 0), a3 = LDAF(3, 1, 0);
      if (t < GM_NT - 1) { stageB(nb, 0, k1); stageB(nb, 1, k1); }
      __builtin_amdgcn_s_barrier();
      __builtin_amdgcn_s_setprio(1);
      MROW(1, 0, a0) MROW(1, 1, a1) MROW(1, 2, a2) MROW(1, 3, a3)
      __builtin_amdgcn_s_setprio(0);
      __builtin_amdgcn_s_barrier();
    }
    {  // P2
      bf16x8 a0 = LDAF(0, 0, 1), a1 = LDAF(1, 0, 1), a2 = LDAF(2, 0, 1), a3 = LDAF(3, 0, 1);
      bf0 = LDBF(0, 1); bf1 = LDBF(1, 1); bf2 = LDBF(2, 1); bf3 = LDBF(3, 1);
      __builtin_amdgcn_s_barrier();
      __builtin_amdgcn_s_setprio(1);
      MROW(0, 0, a0) MROW(0, 1, a1) MROW(0, 2, a2) MROW(0, 3, a3)
      __builtin_amdgcn_s_setprio(0);
      __builtin_amdgcn_s_barrier();
    }
    {  // P3
      bf16x8 a0 = LDAF(0, 1, 1), a1 = LDAF(1, 1, 1), a2 = LDAF(2, 1, 1), a3 = LDAF(3, 1, 1);
      __builtin_amdgcn_s_barrier();
      __builtin_amdgcn_s_setprio(1);
      MROW(1, 0, a0) MROW(1, 1, a1) MROW(1, 2, a2) MROW(1, 3, a3)
      __builtin_amdgcn_s_setprio(0);
    }
  }

#pragma unroll
  for (int mf = 0; mf < 8; ++mf)
#pragma unroll
    for (int nf = 0; nf < 4; ++nf)
#pragma unroll
      for (int i = 0; i < 4; ++i)
        C[(size_t)(m0 + wr * 128 + mf * 16 + g * 4 + i) * QKV_LD +
          n0 + wc * 64 + nf * 16 + l15] = (bf16_t)acc[mf][nf][i];
}

// ---------------- 128x128 GEMM (m97 structure) for the Wo projection, f32 out
__global__ __launch_bounds__(256) void gemm_bt(
    const bf16_t* __restrict__ A, int lda, const bf16_t* __restrict__ Bt,
    float* __restrict__ C, int M, int N, int K) {
  __shared__ __align__(16) bf16_t As[128 * 32];
  __shared__ __align__(16) bf16_t Bs[128 * 32];
  // T1: 256 blocks, 32/XCD = 4 M-rows x all 8 N-cols
  const int wg = blockIdx.x + 8 * blockIdx.y;
  const int swz = (wg & 7) * 32 + (wg >> 3);
  const int bx = swz & 7, by = swz >> 3;
  const int m0 = by * 128, n0 = bx * 128;
  const int tid = threadIdx.x;
  const int w = tid >> 6, lane = tid & 63;
  const int wr = w >> 1, wc = w & 1;
  const int g = lane >> 4, l15 = lane & 15;
  const int srow = lane >> 2, ske = (lane & 3) * 8;

  f32x4 acc[4][4] = {};

  for (int k0 = 0; k0 < K; k0 += 32) {
    __syncthreads();
#pragma unroll
    for (int p = 0; p < 2; ++p) {
      const int chunk = p * 4 + w;
      const int row = chunk * 16 + srow;
      gload_lds16(A + (size_t)(m0 + row) * lda + k0 + ske, As + chunk * 512);
      gload_lds16(Bt + (size_t)(n0 + row) * K + k0 + ske, Bs + chunk * 512);
    }
    __syncthreads();
    bf16x8 af[4], bfr[4];
#pragma unroll
    for (int r = 0; r < 4; ++r)
      af[r] = *(const bf16x8*)(As + (wr * 64 + r * 16 + l15) * 32 + g * 8);
#pragma unroll
    for (int c = 0; c < 4; ++c)
      bfr[c] = *(const bf16x8*)(Bs + (wc * 64 + c * 16 + l15) * 32 + g * 8);
#pragma unroll
    for (int r = 0; r < 4; ++r)
#pragma unroll
      for (int c = 0; c < 4; ++c)
        acc[r][c] = mfma16(af[r], bfr[c], acc[r][c]);
  }

#pragma unroll
  for (int r = 0; r < 4; ++r)
#pragma unroll
    for (int c = 0; c < 4; ++c)
#pragma unroll
      for (int i = 0; i < 4; ++i)
        C[(size_t)(m0 + wr * 64 + r * 16 + g * 4 + i) * N +
          n0 + wc * 64 + c * 16 + l15] = acc[r][c][i];
}

// ---------------- flash sliding-window attention, double-buffered staging
__global__ __launch_bounds__(256) void attn_kernel(
    bf16_t* __restrict__ QKV, const bf16_t* __restrict__ Vt) {
  __shared__ __align__(16) bf16_t Kl[2][64 * 64];
  __shared__ __align__(16) bf16_t Vl[2][64 * 64];

  const int qt = ((blockIdx.x & 7) << 2) | (blockIdx.x >> 3);
  const int bh = blockIdx.y;
  const int b = bh >> 4, h = bh & 15;
  const int q0 = qt * 64;
  const int tid = threadIdx.x, w = tid >> 6, lane = tid & 63;
  const int g = lane >> 4, l15 = lane & 15, gh = g >> 1;
  const int wrow0 = q0 + w * 16;
  const int myrow = wrow0 + l15;
  const int sub = lane >> 3, jj = lane & 7;
  const int sw = l15 & 7;

  auto stage = [&](int bufi, int kt) {
#pragma unroll
    for (int cc = 0; cc < 2; ++cc) {
      const int chunk = w * 2 + cc;
      const int row = chunk * 8 + sub;
      const int sj = jj ^ sub;
      gload_lds16(QKV + ((size_t)b * T_SZ + kt + row) * QKV_LD + 1024 + h * D_SZ + sj * 8,
                  &Kl[bufi][chunk * 512]);
      gload_lds16(Vt + ((size_t)bh * D_SZ + row) * T_SZ + kt + sj * 8,
                  &Vl[bufi][chunk * 512]);
    }
  };

  bf16x8 qf[2];
  {
    const bf16_t* qptr = QKV + ((size_t)b * T_SZ + myrow) * QKV_LD + h * D_SZ;
    const float QSC = 0.125f * 1.44269504f;
#pragma unroll
    for (int c2 = 0; c2 < 2; ++c2) {
      bf16x8 t = *(const bf16x8*)(qptr + c2 * 32 + g * 8);
      bf16x8 o;
#pragma unroll
      for (int j = 0; j < 8; ++j) o[j] = (bf16_t)((float)t[j] * QSC);
      qf[c2] = o;
    }
  }

  float m_s = -1e30f, l_s = 0.f;
  f32x4 oacc[4] = {};

  int kstart = q0 - (WIN - 1);
  if (kstart < 0) kstart = 0;
  kstart &= ~63;
  const int nt = (q0 + 64 - kstart) >> 6;

  stage(0, kstart);

  for (int it = 0; it < nt; ++it) {
    const int kt = kstart + (it << 6);
    const int cur = it & 1;
    if (it + 1 < nt) {
      stage(cur ^ 1, kt + 64);
      asm volatile("s_waitcnt vmcnt(4)" ::: "memory");
    } else {
      asm volatile("s_waitcnt vmcnt(0)" ::: "memory");
    }
    __builtin_amdgcn_s_barrier();
    __builtin_amdgcn_sched_barrier(0);

    f32x4 s[4] = {};
#pragma unroll
    for (int t = 0; t < 4; ++t) {
      const bf16_t* kbase = &Kl[cur][(t * 16 + l15) * 64];
#pragma unroll
      for (int c2 = 0; c2 < 2; ++c2) {
        const bf16x8 kf = *(const bf16x8*)(kbase + (((c2 * 4 + g) ^ sw) << 3));
        s[t] = mfma16(kf, qf[c2], s[t]);
      }
    }

    const bool interior = (kt + 63 <= wrow0) && (kt >= wrow0 + 15 - (WIN - 1));
    float sv[4][4];
    if (interior) {
#pragma unroll
      for (int t = 0; t < 4; ++t)
#pragma unroll
        for (int i = 0; i < 4; ++i) sv[t][i] = s[t][i];
    } else {
#pragma unroll
      for (int t = 0; t < 4; ++t)
#pragma unroll
        for (int i = 0; i < 4; ++i) {
          const int kk = kt + t * 16 + g * 4 + i;
          sv[t][i] = (kk <= myrow && kk > myrow - WIN) ? s[t][i] : -1e30f;
        }
    }

    float mx = sv[0][0];
#pragma unroll
    for (int t = 0; t < 4; ++t)
#pragma unroll
      for (int i = 0; i < 4; ++i)
        if (t || i) mx = fmaxf(mx, sv[t][i]);
    mx = fmaxf(mx, __shfl_xor(mx, 16));
    mx = fmaxf(mx, __shfl_xor(mx, 32));

    float mbase;
    const bool defer = __all(mx <= m_s + 8.f);
    if (defer) {
      mbase = m_s;
    } else {
      const float mnew = fmaxf(m_s, mx);
      const float scl = exp2f(m_s - mnew);
      m_s = mnew;
      mbase = (mnew > -1e29f) ? mnew : 1e30f;
      float sc4[4];
#pragma unroll
      for (int i = 0; i < 4; ++i) sc4[i] = __shfl(scl, g * 4 + i, 16);
#pragma unroll
      for (int c = 0; c < 4; ++c)
#pragma unroll
        for (int i = 0; i < 4; ++i) oacc[c][i] *= sc4[i];
      l_s *= scl;
    }

    float p[4][4];
    float rsum = 0.f;
#pragma unroll
    for (int t = 0; t < 4; ++t)
#pragma unroll
      for (int i = 0; i < 4; ++i) {
        p[t][i] = exp2f(sv[t][i] - mbase);
        rsum += p[t][i];
      }
    rsum += __shfl_xor(rsum, 16);
    rsum += __shfl_xor(rsum, 32);
    l_s += rsum;

    u32 Wp[4][2];
#pragma unroll
    for (int t = 0; t < 4; ++t)
#pragma unroll
      for (int w2 = 0; w2 < 2; ++w2) {
        union { bf16_t hh[2]; u32 uu; } pk;
        pk.hh[0] = (bf16_t)p[t][2 * w2];
        pk.hh[1] = (bf16_t)p[t][2 * w2 + 1];
        Wp[t][w2] = pk.uu;
      }

#pragma unroll
    for (int kp = 0; kp < 2; ++kp) {
      const u32 lo0 = Wp[2 * kp][0], lo1 = Wp[2 * kp][1];
      const u32 hi0 = Wp[2 * kp + 1][0], hi1 = Wp[2 * kp + 1][1];
      union { u32 u[4]; bf16x8 v; } pa;
      pa.u[0] = gh ? hi0 : lo0;
      pa.u[1] = gh ? hi1 : lo1;
      pa.u[2] = (u32)__shfl_xor((int)(gh ? lo0 : hi0), 32);
      pa.u[3] = (u32)__shfl_xor((int)(gh ? lo1 : hi1), 32);

      const int tA = 2 * kp + gh;
      const int low = (g & 1) * 4;
      const int cA = ((tA * 2 + gh) ^ sw) << 3;
      const int cB = ((tA * 2 + (gh ^ 1)) ^ sw) << 3;
#pragma unroll
      for (int c = 0; c < 4; ++c) {
        const bf16_t* vbase = &Vl[cur][(c * 16 + l15) * 64];
        union { bf16x4 h[2]; bf16x8 v; } vv;
        vv.h[0] = *(const bf16x4*)(vbase + cA + low);
        vv.h[1] = *(const bf16x4*)(vbase + cB + low);
        oacc[c] = mfma16(pa.v, vv.v, oacc[c]);
      }
    }
    __builtin_amdgcn_sched_barrier(0);
    __builtin_amdgcn_s_barrier();
  }

  const float invl = 1.0f / l_s;
  float inv4[4];
#pragma unroll
  for (int i = 0; i < 4; ++i) inv4[i] = __shfl(invl, g * 4 + i, 16);
#pragma unroll
  for (int i = 0; i < 4; ++i) {
    const size_t ro = ((size_t)b * T_SZ + wrow0 + g * 4 + i) * QKV_LD + 2048 + h * D_SZ;
#pragma unroll
    for (int c = 0; c < 4; ++c)
      QKV[ro + c * 16 + l15] = (bf16_t)(oacc[c][i] * inv4[i]);
  }
}

extern "C" void kernel_launch(void* const* d_in, const int* in_sizes, int n_in,
                              void* d_out, int out_size, void* d_ws, size_t ws_size,
                              hipStream_t stream) {
  const float* x = (const float*)d_in[0];
  const float* Wq = (const float*)d_in[1];
  const float* Wk = (const float*)d_in[2];
  const float* Wv = (const float*)d_in[3];
  const float* Wo = (const float*)d_in[4];
  float* out = (float*)d_out;
  char* ws = (char*)d_ws;
  const size_t MB = 1ull << 20;
  bf16_t* xb = (bf16_t*)(ws);                // [4096][1024]; becomes Vt after QKV gemm
  bf16_t* Vtp = (bf16_t*)(ws);               // Vt [32][64][2048] overlays xb
  bf16_t* QKVb = (bf16_t*)(ws + 8 * MB);     // [4096][3072]; V-cols become attn out
  bf16_t* WqT = (bf16_t*)(ws + 32 * MB);     // [3072][1024] combined (q|k|v)
  bf16_t* WkT = (bf16_t*)(ws + 34 * MB);
  bf16_t* WvT = (bf16_t*)(ws + 36 * MB);
  bf16_t* WoT = (bf16_t*)(ws + 38 * MB);

  prep<<<dim3(32, 32, 5), 256, 0, stream>>>(x, xb, Wq, Wk, Wv, Wo,
                                            WqT, WkT, WvT, WoT);
  gemm256<<<dim3(12, 16), 512, 0, stream>>>(xb, WqT, QKVb);
  transpose_v<<<dim3(64, 2, 32), 256, 0, stream>>>(QKVb, Vtp);  // clobbers xb (done)
  attn_kernel<<<dim3(T_SZ / 64, B_SZ * H_CNT), 256, 0, stream>>>(QKVb, Vtp);
  gemm_bt<<<dim3(8, 32), 256, 0, stream>>>(QKVb + 2048, QKV_LD, WoT, out,
                                           B_SZ * T_SZ, C_SZ, C_SZ);
}

// Round 5
// 91.591 us; speedup vs baseline: 1.5442x; 1.1999x over previous
//
#include <hip/hip_runtime.h>

#define B_SZ 2
#define T_SZ 2048
#define C_SZ 1024
#define K_SZ 1024
#define QKV_LD 3072
#define H_CNT 16
#define D_SZ 64
#define WIN 512

typedef __bf16 bf16_t;
typedef bf16_t bf16x8 __attribute__((ext_vector_type(8)));
typedef bf16_t bf16x4 __attribute__((ext_vector_type(4)));
typedef float f32x4 __attribute__((ext_vector_type(4)));
typedef unsigned int u32;

__device__ __forceinline__ f32x4 mfma16(bf16x8 a, bf16x8 b, f32x4 c) {
  return __builtin_amdgcn_mfma_f32_16x16x32_bf16(a, b, c, 0, 0, 0);
}

__device__ __forceinline__ void gload_lds16(const void* gsrc, void* ldst) {
  auto g = (__attribute__((address_space(1))) void*)(unsigned long long)gsrc;
  auto l = (__attribute__((address_space(3))) void*)(unsigned int)(unsigned long long)ldst;
  __builtin_amdgcn_global_load_lds(g, l, 16, 0, 0);
}

// ---------------- prep: weight transpose+convert (z<4) | x convert (z==4)
__global__ __launch_bounds__(256) void prep(
    const float* __restrict__ x, bf16_t* __restrict__ xb,
    const float* __restrict__ W0, const float* __restrict__ W1,
    const float* __restrict__ W2, const float* __restrict__ W3,
    bf16_t* __restrict__ T0, bf16_t* __restrict__ T1,
    bf16_t* __restrict__ T2, bf16_t* __restrict__ T3) {
  if (blockIdx.z == 4) {
    const int base = (blockIdx.y * 32 + blockIdx.x) * 256 + threadIdx.x;
#pragma unroll
    for (int j = 0; j < 4; ++j) {
      const int idx = base + j * 262144;
      const float4 v = ((const float4*)x)[idx];
      bf16x4 r;
      r[0] = (bf16_t)v.x; r[1] = (bf16_t)v.y; r[2] = (bf16_t)v.z; r[3] = (bf16_t)v.w;
      ((bf16x4*)xb)[idx] = r;
    }
    return;
  }
  __shared__ float tile[32][33];
  const float* W = blockIdx.z == 0 ? W0 : blockIdx.z == 1 ? W1 : blockIdx.z == 2 ? W2 : W3;
  bf16_t* Tt = blockIdx.z == 0 ? T0 : blockIdx.z == 1 ? T1 : blockIdx.z == 2 ? T2 : T3;
  const int tx = threadIdx.x & 31, ty = threadIdx.x >> 5;
  const int r0 = blockIdx.y * 32, c0 = blockIdx.x * 32;
#pragma unroll
  for (int i = 0; i < 4; ++i)
    tile[ty + i * 8][tx] = W[(size_t)(r0 + ty + i * 8) * C_SZ + c0 + tx];
  __syncthreads();
#pragma unroll
  for (int i = 0; i < 4; ++i)
    Tt[(size_t)(c0 + ty + i * 8) * C_SZ + r0 + tx] = (bf16_t)tile[tx][ty + i * 8];
}

// ---------------- V transpose: QKV V-cols -> Vt [B*H][D][T]
__global__ __launch_bounds__(256) void transpose_v(const bf16_t* __restrict__ QKV,
                                                   bf16_t* __restrict__ Vt) {
  __shared__ bf16_t tile[32][33];
  const int t0 = blockIdx.x * 32, d0 = blockIdx.y * 32, bh = blockIdx.z;
  const int b = bh >> 4, h = bh & 15;
  const int tx = threadIdx.x & 31, ty = threadIdx.x >> 5;
#pragma unroll
  for (int i = 0; i < 4; ++i)
    tile[ty + i * 8][tx] =
        QKV[((size_t)b * T_SZ + t0 + ty + i * 8) * QKV_LD + 2048 + h * D_SZ + d0 + tx];
  __syncthreads();
#pragma unroll
  for (int i = 0; i < 4; ++i)
    Vt[((size_t)bh * D_SZ + d0 + ty + i * 8) * T_SZ + t0 + tx] = tile[tx][ty + i * 8];
}

// ---------------- 256x192 8-phase GEMM: C[M,N] = A[M,K] @ Bt[N,K]^T
// M=4096, N=3072, K=1024. Grid 16x16 = 256 blocks = 1/CU exactly.
// 8 waves (2Mx4N), BK=64, 112KB dbuf LDS, XOR chunk-swizzle both sides.
#define GM_NT 16  // K / 64

__global__ __launch_bounds__(512, 2) void gemm256(
    const bf16_t* __restrict__ A, const bf16_t* __restrict__ Bt,
    bf16_t* __restrict__ C) {
  __shared__ __align__(16) bf16_t As[2][256 * 64];
  __shared__ __align__(16) bf16_t Bs[2][192 * 64];
  // T1: 256 blocks, 32/XCD (2 M-rows x 16 N-cols per XCD)
  const int wg = blockIdx.x + 16 * blockIdx.y;
  const int swz = (wg & 7) * 32 + (wg >> 3);
  const int bx = swz & 15, by = swz >> 4;
  const int m0 = by * 256, n0 = bx * 192;
  const int tid = threadIdx.x, w = tid >> 6, lane = tid & 63;
  const int wr = w >> 2, wc = w & 3;
  const int g = lane >> 4, l15 = lane & 15, sw = l15 & 7;
  const int srow = lane >> 3, sj = lane & 7;

  f32x4 acc[8][3] = {};

  auto stageA = [&](int buf, int half, int k0) {
#pragma unroll
    for (int q8 = 0; q8 < 2; ++q8) {
      const int rg = w * 16 + q8 * 8;
      gload_lds16(A + (size_t)(m0 + half * 128 + rg + srow) * K_SZ + k0 + ((sj ^ srow) << 3),
                  &As[buf][half * 8192 + rg * 64]);
    }
  };
  auto stageB = [&](int buf, int third, int k0) {
    const int rg = third * 64 + w * 8;
    gload_lds16(Bt + (size_t)(n0 + rg + srow) * K_SZ + k0 + ((sj ^ srow) << 3),
                &Bs[buf][rg * 64]);
  };

  stageA(0, 0, 0); stageA(0, 1, 0);
  stageB(0, 0, 0); stageB(0, 1, 0); stageB(0, 2, 0);

#define LDAF(MF4, MH, KK) \
  (*(const bf16x8*)&As[buf][(wr * 128 + ((MH) * 4 + (MF4)) * 16 + l15) * 64 + \
                            ((((KK) << 2) | g) ^ sw) * 8])
#define LDBF(NF, KK) \
  (*(const bf16x8*)&Bs[buf][(wc * 48 + (NF) * 16 + l15) * 64 + \
                            ((((KK) << 2) | g) ^ sw) * 8])
#define MROW(MH, MF, AF)                                   \
  acc[(MH) * 4 + (MF)][0] = mfma16(AF, bf0, acc[(MH) * 4 + (MF)][0]); \
  acc[(MH) * 4 + (MF)][1] = mfma16(AF, bf1, acc[(MH) * 4 + (MF)][1]); \
  acc[(MH) * 4 + (MF)][2] = mfma16(AF, bf2, acc[(MH) * 4 + (MF)][2]);

#pragma unroll 2
  for (int t = 0; t < GM_NT; ++t) {
    const int buf = t & 1, nb = buf ^ 1;
    const int k1 = (t + 1) * 64;
    asm volatile("s_waitcnt vmcnt(0)" ::: "memory");
    __builtin_amdgcn_s_barrier();

    bf16x8 bf0, bf1, bf2;
    {  // P0: (mh0, kk0) + stage A of t+1
      bf16x8 a0 = LDAF(0, 0, 0), a1 = LDAF(1, 0, 0), a2 = LDAF(2, 0, 0), a3 = LDAF(3, 0, 0);
      bf0 = LDBF(0, 0); bf1 = LDBF(1, 0); bf2 = LDBF(2, 0);
      if (t < GM_NT - 1) { stageA(nb, 0, k1); stageA(nb, 1, k1); }
      __builtin_amdgcn_s_barrier();
      __builtin_amdgcn_s_setprio(1);
      MROW(0, 0, a0) MROW(0, 1, a1) MROW(0, 2, a2) MROW(0, 3, a3)
      __builtin_amdgcn_s_setprio(0);
      __builtin_amdgcn_s_barrier();
    }
    {  // P1: (mh1, kk0) + stage B of t+1
      bf16x8 a0 = LDAF(0, 1, 0), a1 = LDAF(1, 1, 0), a2 = LDAF(2, 1, 0), a3 = LDAF(3, 1, 0);
      if (t < GM_NT - 1) { stageB(nb, 0, k1); stageB(nb, 1, k1); stageB(nb, 2, k1); }
      __builtin_amdgcn_s_barrier();
      __builtin_amdgcn_s_setprio(1);
      MROW(1, 0, a0) MROW(1, 1, a1) MROW(1, 2, a2) MROW(1, 3, a3)
      __builtin_amdgcn_s_setprio(0);
      __builtin_amdgcn_s_barrier();
    }
    {  // P2: (mh0, kk1)
      bf16x8 a0 = LDAF(0, 0, 1), a1 = LDAF(1, 0, 1), a2 = LDAF(2, 0, 1), a3 = LDAF(3, 0, 1);
      bf0 = LDBF(0, 1); bf1 = LDBF(1, 1); bf2 = LDBF(2, 1);
      __builtin_amdgcn_s_barrier();
      __builtin_amdgcn_s_setprio(1);
      MROW(0, 0, a0) MROW(0, 1, a1) MROW(0, 2, a2) MROW(0, 3, a3)
      __builtin_amdgcn_s_setprio(0);
      __builtin_amdgcn_s_barrier();
    }
    {  // P3: (mh1, kk1)
      bf16x8 a0 = LDAF(0, 1, 1), a1 = LDAF(1, 1, 1), a2 = LDAF(2, 1, 1), a3 = LDAF(3, 1, 1);
      __builtin_amdgcn_s_barrier();
      __builtin_amdgcn_s_setprio(1);
      MROW(1, 0, a0) MROW(1, 1, a1) MROW(1, 2, a2) MROW(1, 3, a3)
      __builtin_amdgcn_s_setprio(0);
    }
  }

#pragma unroll
  for (int mf = 0; mf < 8; ++mf)
#pragma unroll
    for (int nf = 0; nf < 3; ++nf)
#pragma unroll
      for (int i = 0; i < 4; ++i)
        C[(size_t)(m0 + wr * 128 + mf * 16 + g * 4 + i) * QKV_LD +
          n0 + wc * 48 + nf * 16 + l15] = (bf16_t)acc[mf][nf][i];
}

// ---------------- 128x128 dbuf BK=64 GEMM for the Wo projection, f32 out
// 8 waves (2Mx4N, wave out 64x32), 64KB LDS dbuf -> 2 blocks/CU,
// one vmcnt(0)+barrier per K-tile, staging issued at tile top.
__global__ __launch_bounds__(512, 4) void gemm128(
    const bf16_t* __restrict__ A, int lda, const bf16_t* __restrict__ Bt,
    float* __restrict__ C, int N) {
  __shared__ __align__(16) bf16_t As[2][128 * 64];
  __shared__ __align__(16) bf16_t Bs[2][128 * 64];
  // T1: 256 blocks, 32/XCD (4 M-rows x 8 N-cols per XCD)
  const int wg = blockIdx.x + 8 * blockIdx.y;
  const int swz = (wg & 7) * 32 + (wg >> 3);
  const int bx = swz & 7, by = swz >> 3;
  const int m0 = by * 128, n0 = bx * 128;
  const int tid = threadIdx.x, w = tid >> 6, lane = tid & 63;
  const int wr = w >> 2, wc = w & 3;
  const int g = lane >> 4, l15 = lane & 15, sw = l15 & 7;
  const int srow = lane >> 3, sj = lane & 7;

  f32x4 acc[4][2] = {};

  auto stage = [&](int buf, int k0) {
#pragma unroll
    for (int half = 0; half < 2; ++half) {
      const int rg = half * 64 + w * 8;
      gload_lds16(A + (size_t)(m0 + rg + srow) * lda + k0 + ((sj ^ srow) << 3),
                  &As[buf][rg * 64]);
      gload_lds16(Bt + (size_t)(n0 + rg + srow) * K_SZ + k0 + ((sj ^ srow) << 3),
                  &Bs[buf][rg * 64]);
    }
  };

  stage(0, 0);

#pragma unroll 2
  for (int t = 0; t < GM_NT; ++t) {
    const int buf = t & 1;
    asm volatile("s_waitcnt vmcnt(0)" ::: "memory");
    __builtin_amdgcn_s_barrier();
    if (t < GM_NT - 1) stage(buf ^ 1, (t + 1) * 64);
#pragma unroll
    for (int kk = 0; kk < 2; ++kk) {
      bf16x8 af[4], bfr[2];
#pragma unroll
      for (int mf = 0; mf < 4; ++mf)
        af[mf] = *(const bf16x8*)&As[buf][(wr * 64 + mf * 16 + l15) * 64 +
                                          (((kk << 2) | g) ^ sw) * 8];
#pragma unroll
      for (int nf = 0; nf < 2; ++nf)
        bfr[nf] = *(const bf16x8*)&Bs[buf][(wc * 32 + nf * 16 + l15) * 64 +
                                           (((kk << 2) | g) ^ sw) * 8];
      __builtin_amdgcn_s_setprio(1);
#pragma unroll
      for (int mf = 0; mf < 4; ++mf)
#pragma unroll
        for (int nf = 0; nf < 2; ++nf)
          acc[mf][nf] = mfma16(af[mf], bfr[nf], acc[mf][nf]);
      __builtin_amdgcn_s_setprio(0);
    }
  }

#pragma unroll
  for (int mf = 0; mf < 4; ++mf)
#pragma unroll
    for (int nf = 0; nf < 2; ++nf)
#pragma unroll
      for (int i = 0; i < 4; ++i)
        C[(size_t)(m0 + wr * 64 + mf * 16 + g * 4 + i) * N +
          n0 + wc * 32 + nf * 16 + l15] = acc[mf][nf][i];
}

// ---------------- flash sliding-window attention, double-buffered staging
__global__ __launch_bounds__(256) void attn_kernel(
    bf16_t* __restrict__ QKV, const bf16_t* __restrict__ Vt) {
  __shared__ __align__(16) bf16_t Kl[2][64 * 64];
  __shared__ __align__(16) bf16_t Vl[2][64 * 64];

  const int qt = ((blockIdx.x & 7) << 2) | (blockIdx.x >> 3);
  const int bh = blockIdx.y;
  const int b = bh >> 4, h = bh & 15;
  const int q0 = qt * 64;
  const int tid = threadIdx.x, w = tid >> 6, lane = tid & 63;
  const int g = lane >> 4, l15 = lane & 15, gh = g >> 1;
  const int wrow0 = q0 + w * 16;
  const int myrow = wrow0 + l15;
  const int sub = lane >> 3, jj = lane & 7;
  const int sw = l15 & 7;

  auto stage = [&](int bufi, int kt) {
#pragma unroll
    for (int cc = 0; cc < 2; ++cc) {
      const int chunk = w * 2 + cc;
      const int row = chunk * 8 + sub;
      const int sj = jj ^ sub;
      gload_lds16(QKV + ((size_t)b * T_SZ + kt + row) * QKV_LD + 1024 + h * D_SZ + sj * 8,
                  &Kl[bufi][chunk * 512]);
      gload_lds16(Vt + ((size_t)bh * D_SZ + row) * T_SZ + kt + sj * 8,
                  &Vl[bufi][chunk * 512]);
    }
  };

  bf16x8 qf[2];
  {
    const bf16_t* qptr = QKV + ((size_t)b * T_SZ + myrow) * QKV_LD + h * D_SZ;
    const float QSC = 0.125f * 1.44269504f;
#pragma unroll
    for (int c2 = 0; c2 < 2; ++c2) {
      bf16x8 t = *(const bf16x8*)(qptr + c2 * 32 + g * 8);
      bf16x8 o;
#pragma unroll
      for (int j = 0; j < 8; ++j) o[j] = (bf16_t)((float)t[j] * QSC);
      qf[c2] = o;
    }
  }

  float m_s = -1e30f, l_s = 0.f;
  f32x4 oacc[4] = {};

  int kstart = q0 - (WIN - 1);
  if (kstart < 0) kstart = 0;
  kstart &= ~63;
  const int nt = (q0 + 64 - kstart) >> 6;

  stage(0, kstart);

  for (int it = 0; it < nt; ++it) {
    const int kt = kstart + (it << 6);
    const int cur = it & 1;
    if (it + 1 < nt) {
      stage(cur ^ 1, kt + 64);
      asm volatile("s_waitcnt vmcnt(4)" ::: "memory");
    } else {
      asm volatile("s_waitcnt vmcnt(0)" ::: "memory");
    }
    __builtin_amdgcn_s_barrier();
    __builtin_amdgcn_sched_barrier(0);

    f32x4 s[4] = {};
#pragma unroll
    for (int t = 0; t < 4; ++t) {
      const bf16_t* kbase = &Kl[cur][(t * 16 + l15) * 64];
#pragma unroll
      for (int c2 = 0; c2 < 2; ++c2) {
        const bf16x8 kf = *(const bf16x8*)(kbase + (((c2 * 4 + g) ^ sw) << 3));
        s[t] = mfma16(kf, qf[c2], s[t]);
      }
    }

    const bool interior = (kt + 63 <= wrow0) && (kt >= wrow0 + 15 - (WIN - 1));
    float sv[4][4];
    if (interior) {
#pragma unroll
      for (int t = 0; t < 4; ++t)
#pragma unroll
        for (int i = 0; i < 4; ++i) sv[t][i] = s[t][i];
    } else {
#pragma unroll
      for (int t = 0; t < 4; ++t)
#pragma unroll
        for (int i = 0; i < 4; ++i) {
          const int kk = kt + t * 16 + g * 4 + i;
          sv[t][i] = (kk <= myrow && kk > myrow - WIN) ? s[t][i] : -1e30f;
        }
    }

    float mx = sv[0][0];
#pragma unroll
    for (int t = 0; t < 4; ++t)
#pragma unroll
      for (int i = 0; i < 4; ++i)
        if (t || i) mx = fmaxf(mx, sv[t][i]);
    mx = fmaxf(mx, __shfl_xor(mx, 16));
    mx = fmaxf(mx, __shfl_xor(mx, 32));

    float mbase;
    const bool defer = __all(mx <= m_s + 8.f);
    if (defer) {
      mbase = m_s;
    } else {
      const float mnew = fmaxf(m_s, mx);
      const float scl = exp2f(m_s - mnew);
      m_s = mnew;
      mbase = (mnew > -1e29f) ? mnew : 1e30f;
      float sc4[4];
#pragma unroll
      for (int i = 0; i < 4; ++i) sc4[i] = __shfl(scl, g * 4 + i, 16);
#pragma unroll
      for (int c = 0; c < 4; ++c)
#pragma unroll
        for (int i = 0; i < 4; ++i) oacc[c][i] *= sc4[i];
      l_s *= scl;
    }

    float p[4][4];
    float rsum = 0.f;
#pragma unroll
    for (int t = 0; t < 4; ++t)
#pragma unroll
      for (int i = 0; i < 4; ++i) {
        p[t][i] = exp2f(sv[t][i] - mbase);
        rsum += p[t][i];
      }
    rsum += __shfl_xor(rsum, 16);
    rsum += __shfl_xor(rsum, 32);
    l_s += rsum;

    u32 Wp[4][2];
#pragma unroll
    for (int t = 0; t < 4; ++t)
#pragma unroll
      for (int w2 = 0; w2 < 2; ++w2) {
        union { bf16_t hh[2]; u32 uu; } pk;
        pk.hh[0] = (bf16_t)p[t][2 * w2];
        pk.hh[1] = (bf16_t)p[t][2 * w2 + 1];
        Wp[t][w2] = pk.uu;
      }

#pragma unroll
    for (int kp = 0; kp < 2; ++kp) {
      const u32 lo0 = Wp[2 * kp][0], lo1 = Wp[2 * kp][1];
      const u32 hi0 = Wp[2 * kp + 1][0], hi1 = Wp[2 * kp + 1][1];
      union { u32 u[4]; bf16x8 v; } pa;
      pa.u[0] = gh ? hi0 : lo0;
      pa.u[1] = gh ? hi1 : lo1;
      pa.u[2] = (u32)__shfl_xor((int)(gh ? lo0 : hi0), 32);
      pa.u[3] = (u32)__shfl_xor((int)(gh ? lo1 : hi1), 32);

      const int tA = 2 * kp + gh;
      const int low = (g & 1) * 4;
      const int cA = ((tA * 2 + gh) ^ sw) << 3;
      const int cB = ((tA * 2 + (gh ^ 1)) ^ sw) << 3;
#pragma unroll
      for (int c = 0; c < 4; ++c) {
        const bf16_t* vbase = &Vl[cur][(c * 16 + l15) * 64];
        union { bf16x4 h[2]; bf16x8 v; } vv;
        vv.h[0] = *(const bf16x4*)(vbase + cA + low);
        vv.h[1] = *(const bf16x4*)(vbase + cB + low);
        oacc[c] = mfma16(pa.v, vv.v, oacc[c]);
      }
    }
    __builtin_amdgcn_sched_barrier(0);
    __builtin_amdgcn_s_barrier();
  }

  const float invl = 1.0f / l_s;
  float inv4[4];
#pragma unroll
  for (int i = 0; i < 4; ++i) inv4[i] = __shfl(invl, g * 4 + i, 16);
#pragma unroll
  for (int i = 0; i < 4; ++i) {
    const size_t ro = ((size_t)b * T_SZ + wrow0 + g * 4 + i) * QKV_LD + 2048 + h * D_SZ;
#pragma unroll
    for (int c = 0; c < 4; ++c)
      QKV[ro + c * 16 + l15] = (bf16_t)(oacc[c][i] * inv4[i]);
  }
}

extern "C" void kernel_launch(void* const* d_in, const int* in_sizes, int n_in,
                              void* d_out, int out_size, void* d_ws, size_t ws_size,
                              hipStream_t stream) {
  const float* x = (const float*)d_in[0];
  const float* Wq = (const float*)d_in[1];
  const float* Wk = (const float*)d_in[2];
  const float* Wv = (const float*)d_in[3];
  const float* Wo = (const float*)d_in[4];
  float* out = (float*)d_out;
  char* ws = (char*)d_ws;
  const size_t MB = 1ull << 20;
  bf16_t* xb = (bf16_t*)(ws);                // [4096][1024]; becomes Vt after QKV gemm
  bf16_t* Vtp = (bf16_t*)(ws);               // Vt [32][64][2048] overlays xb
  bf16_t* QKVb = (bf16_t*)(ws + 8 * MB);     // [4096][3072]; V-cols become attn out
  bf16_t* WqT = (bf16_t*)(ws + 32 * MB);     // [3072][1024] combined (q|k|v)
  bf16_t* WkT = (bf16_t*)(ws + 34 * MB);
  bf16_t* WvT = (bf16_t*)(ws + 36 * MB);
  bf16_t* WoT = (bf16_t*)(ws + 38 * MB);

  prep<<<dim3(32, 32, 5), 256, 0, stream>>>(x, xb, Wq, Wk, Wv, Wo,
                                            WqT, WkT, WvT, WoT);
  gemm256<<<dim3(16, 16), 512, 0, stream>>>(xb, WqT, QKVb);
  transpose_v<<<dim3(64, 2, 32), 256, 0, stream>>>(QKVb, Vtp);  // clobbers xb (done)
  attn_kernel<<<dim3(T_SZ / 64, B_SZ * H_CNT), 256, 0, stream>>>(QKVb, Vtp);
  gemm128<<<dim3(8, 32), 512, 0, stream>>>(QKVb + 2048, QKV_LD, WoT, out, C_SZ);
}

// Round 6
// 86.202 us; speedup vs baseline: 1.6407x; 1.0625x over previous
//
#include <hip/hip_runtime.h>

#define B_SZ 2
#define T_SZ 2048
#define C_SZ 1024
#define K_SZ 1024
#define QKV_LD 3072
#define H_CNT 16
#define D_SZ 64
#define WIN 512

typedef __bf16 bf16_t;
typedef bf16_t bf16x8 __attribute__((ext_vector_type(8)));
typedef bf16_t bf16x4 __attribute__((ext_vector_type(4)));
typedef float f32x4 __attribute__((ext_vector_type(4)));
typedef unsigned int u32;

__device__ __forceinline__ f32x4 mfma16(bf16x8 a, bf16x8 b, f32x4 c) {
  return __builtin_amdgcn_mfma_f32_16x16x32_bf16(a, b, c, 0, 0, 0);
}

__device__ __forceinline__ void gload_lds16(const void* gsrc, void* ldst) {
  auto g = (__attribute__((address_space(1))) void*)(unsigned long long)gsrc;
  auto l = (__attribute__((address_space(3))) void*)(unsigned int)(unsigned long long)ldst;
  __builtin_amdgcn_global_load_lds(g, l, 16, 0, 0);
}

// ---------------- prep: weight transpose+convert (z<4) | x convert (z==4)
__global__ __launch_bounds__(256) void prep(
    const float* __restrict__ x, bf16_t* __restrict__ xb,
    const float* __restrict__ W0, const float* __restrict__ W1,
    const float* __restrict__ W2, const float* __restrict__ W3,
    bf16_t* __restrict__ T0, bf16_t* __restrict__ T1,
    bf16_t* __restrict__ T2, bf16_t* __restrict__ T3) {
  if (blockIdx.z == 4) {
    const int base = (blockIdx.y * 32 + blockIdx.x) * 256 + threadIdx.x;
#pragma unroll
    for (int j = 0; j < 4; ++j) {
      const int idx = base + j * 262144;
      const float4 v = ((const float4*)x)[idx];
      bf16x4 r;
      r[0] = (bf16_t)v.x; r[1] = (bf16_t)v.y; r[2] = (bf16_t)v.z; r[3] = (bf16_t)v.w;
      ((bf16x4*)xb)[idx] = r;
    }
    return;
  }
  __shared__ float tile[32][33];
  const float* W = blockIdx.z == 0 ? W0 : blockIdx.z == 1 ? W1 : blockIdx.z == 2 ? W2 : W3;
  bf16_t* Tt = blockIdx.z == 0 ? T0 : blockIdx.z == 1 ? T1 : blockIdx.z == 2 ? T2 : T3;
  const int tx = threadIdx.x & 31, ty = threadIdx.x >> 5;
  const int r0 = blockIdx.y * 32, c0 = blockIdx.x * 32;
#pragma unroll
  for (int i = 0; i < 4; ++i)
    tile[ty + i * 8][tx] = W[(size_t)(r0 + ty + i * 8) * C_SZ + c0 + tx];
  __syncthreads();
#pragma unroll
  for (int i = 0; i < 4; ++i)
    Tt[(size_t)(c0 + ty + i * 8) * C_SZ + r0 + tx] = (bf16_t)tile[tx][ty + i * 8];
}

// ---------------- 256x192 8-phase GEMM: C[M,N] = A[M,K] @ Bt[N,K]^T
// V-columns (col>=2048) are written transposed straight into Vt[bh][d][t]
// (4 accumulator rows = 4 consecutive t -> one 8B store per lane).
#define GM_NT 16  // K / 64

__global__ __launch_bounds__(512, 2) void gemm256(
    const bf16_t* __restrict__ A, const bf16_t* __restrict__ Bt,
    bf16_t* __restrict__ C, bf16_t* __restrict__ Vt) {
  __shared__ __align__(16) bf16_t As[2][256 * 64];
  __shared__ __align__(16) bf16_t Bs[2][192 * 64];
  const int wg = blockIdx.x + 16 * blockIdx.y;
  const int swz = (wg & 7) * 32 + (wg >> 3);
  const int bx = swz & 15, by = swz >> 4;
  const int m0 = by * 256, n0 = bx * 192;
  const int tid = threadIdx.x, w = tid >> 6, lane = tid & 63;
  const int wr = w >> 2, wc = w & 3;
  const int g = lane >> 4, l15 = lane & 15, sw = l15 & 7;
  const int srow = lane >> 3, sj = lane & 7;

  f32x4 acc[8][3] = {};

  auto stageA = [&](int buf, int half, int k0) {
#pragma unroll
    for (int q8 = 0; q8 < 2; ++q8) {
      const int rg = w * 16 + q8 * 8;
      gload_lds16(A + (size_t)(m0 + half * 128 + rg + srow) * K_SZ + k0 + ((sj ^ srow) << 3),
                  &As[buf][half * 8192 + rg * 64]);
    }
  };
  auto stageB = [&](int buf, int third, int k0) {
    const int rg = third * 64 + w * 8;
    gload_lds16(Bt + (size_t)(n0 + rg + srow) * K_SZ + k0 + ((sj ^ srow) << 3),
                &Bs[buf][rg * 64]);
  };

  stageA(0, 0, 0); stageA(0, 1, 0);
  stageB(0, 0, 0); stageB(0, 1, 0); stageB(0, 2, 0);

#define LDAF(MF4, MH, KK) \
  (*(const bf16x8*)&As[buf][(wr * 128 + ((MH) * 4 + (MF4)) * 16 + l15) * 64 + \
                            ((((KK) << 2) | g) ^ sw) * 8])
#define LDBF(NF, KK) \
  (*(const bf16x8*)&Bs[buf][(wc * 48 + (NF) * 16 + l15) * 64 + \
                            ((((KK) << 2) | g) ^ sw) * 8])
#define MROW(MH, MF, AF)                                   \
  acc[(MH) * 4 + (MF)][0] = mfma16(AF, bf0, acc[(MH) * 4 + (MF)][0]); \
  acc[(MH) * 4 + (MF)][1] = mfma16(AF, bf1, acc[(MH) * 4 + (MF)][1]); \
  acc[(MH) * 4 + (MF)][2] = mfma16(AF, bf2, acc[(MH) * 4 + (MF)][2]);

#pragma unroll 2
  for (int t = 0; t < GM_NT; ++t) {
    const int buf = t & 1, nb = buf ^ 1;
    const int k1 = (t + 1) * 64;
    asm volatile("s_waitcnt vmcnt(0)" ::: "memory");
    __builtin_amdgcn_s_barrier();

    bf16x8 bf0, bf1, bf2;
    {  // P0: (mh0, kk0) + stage A of t+1
      bf16x8 a0 = LDAF(0, 0, 0), a1 = LDAF(1, 0, 0), a2 = LDAF(2, 0, 0), a3 = LDAF(3, 0, 0);
      bf0 = LDBF(0, 0); bf1 = LDBF(1, 0); bf2 = LDBF(2, 0);
      if (t < GM_NT - 1) { stageA(nb, 0, k1); stageA(nb, 1, k1); }
      __builtin_amdgcn_s_barrier();
      __builtin_amdgcn_s_setprio(1);
      MROW(0, 0, a0) MROW(0, 1, a1) MROW(0, 2, a2) MROW(0, 3, a3)
      __builtin_amdgcn_s_setprio(0);
      __builtin_amdgcn_s_barrier();
    }
    {  // P1: (mh1, kk0) + stage B of t+1
      bf16x8 a0 = LDAF(0, 1, 0), a1 = LDAF(1, 1, 0), a2 = LDAF(2, 1, 0), a3 = LDAF(3, 1, 0);
      if (t < GM_NT - 1) { stageB(nb, 0, k1); stageB(nb, 1, k1); stageB(nb, 2, k1); }
      __builtin_amdgcn_s_barrier();
      __builtin_amdgcn_s_setprio(1);
      MROW(1, 0, a0) MROW(1, 1, a1) MROW(1, 2, a2) MROW(1, 3, a3)
      __builtin_amdgcn_s_setprio(0);
      __builtin_amdgcn_s_barrier();
    }
    {  // P2: (mh0, kk1)
      bf16x8 a0 = LDAF(0, 0, 1), a1 = LDAF(1, 0, 1), a2 = LDAF(2, 0, 1), a3 = LDAF(3, 0, 1);
      bf0 = LDBF(0, 1); bf1 = LDBF(1, 1); bf2 = LDBF(2, 1);
      __builtin_amdgcn_s_barrier();
      __builtin_amdgcn_s_setprio(1);
      MROW(0, 0, a0) MROW(0, 1, a1) MROW(0, 2, a2) MROW(0, 3, a3)
      __builtin_amdgcn_s_setprio(0);
      __builtin_amdgcn_s_barrier();
    }
    {  // P3: (mh1, kk1)
      bf16x8 a0 = LDAF(0, 1, 1), a1 = LDAF(1, 1, 1), a2 = LDAF(2, 1, 1), a3 = LDAF(3, 1, 1);
      __builtin_amdgcn_s_barrier();
      __builtin_amdgcn_s_setprio(1);
      MROW(1, 0, a0) MROW(1, 1, a1) MROW(1, 2, a2) MROW(1, 3, a3)
      __builtin_amdgcn_s_setprio(0);
    }
  }

#pragma unroll
  for (int mf = 0; mf < 8; ++mf) {
    const int row = m0 + wr * 128 + mf * 16 + g * 4;
#pragma unroll
    for (int nf = 0; nf < 3; ++nf) {
      const int colb = n0 + wc * 48 + nf * 16;
      if (colb >= 2048) {  // V: write transposed to Vt[bh][d][t]
        const int d = colb - 2048 + l15;
        const size_t vo =
            ((size_t)((row >> 11) * 16 + (d >> 6)) * 64 + (d & 63)) * (size_t)T_SZ +
            (row & (T_SZ - 1));
        union { bf16_t h4[4]; uint2 u; } pk;
#pragma unroll
        for (int i = 0; i < 4; ++i) pk.h4[i] = (bf16_t)acc[mf][nf][i];
        *(uint2*)(Vt + vo) = pk.u;
      } else {
#pragma unroll
        for (int i = 0; i < 4; ++i)
          C[(size_t)(row + i) * QKV_LD + colb + l15] = (bf16_t)acc[mf][nf][i];
      }
    }
  }
}

// ---------------- 128x128 dbuf BK=64 GEMM for the Wo projection, f32 out
__global__ __launch_bounds__(512, 4) void gemm128(
    const bf16_t* __restrict__ A, int lda, const bf16_t* __restrict__ Bt,
    float* __restrict__ C, int N) {
  __shared__ __align__(16) bf16_t As[2][128 * 64];
  __shared__ __align__(16) bf16_t Bs[2][128 * 64];
  const int wg = blockIdx.x + 8 * blockIdx.y;
  const int swz = (wg & 7) * 32 + (wg >> 3);
  const int bx = swz & 7, by = swz >> 3;
  const int m0 = by * 128, n0 = bx * 128;
  const int tid = threadIdx.x, w = tid >> 6, lane = tid & 63;
  const int wr = w >> 2, wc = w & 3;
  const int g = lane >> 4, l15 = lane & 15, sw = l15 & 7;
  const int srow = lane >> 3, sj = lane & 7;

  f32x4 acc[4][2] = {};

  auto stage = [&](int buf, int k0) {
#pragma unroll
    for (int half = 0; half < 2; ++half) {
      const int rg = half * 64 + w * 8;
      gload_lds16(A + (size_t)(m0 + rg + srow) * lda + k0 + ((sj ^ srow) << 3),
                  &As[buf][rg * 64]);
      gload_lds16(Bt + (size_t)(n0 + rg + srow) * K_SZ + k0 + ((sj ^ srow) << 3),
                  &Bs[buf][rg * 64]);
    }
  };

  stage(0, 0);

#pragma unroll 2
  for (int t = 0; t < GM_NT; ++t) {
    const int buf = t & 1;
    asm volatile("s_waitcnt vmcnt(0)" ::: "memory");
    __builtin_amdgcn_s_barrier();
    if (t < GM_NT - 1) stage(buf ^ 1, (t + 1) * 64);
#pragma unroll
    for (int kk = 0; kk < 2; ++kk) {
      bf16x8 af[4], bfr[2];
#pragma unroll
      for (int mf = 0; mf < 4; ++mf)
        af[mf] = *(const bf16x8*)&As[buf][(wr * 64 + mf * 16 + l15) * 64 +
                                          (((kk << 2) | g) ^ sw) * 8];
#pragma unroll
      for (int nf = 0; nf < 2; ++nf)
        bfr[nf] = *(const bf16x8*)&Bs[buf][(wc * 32 + nf * 16 + l15) * 64 +
                                           (((kk << 2) | g) ^ sw) * 8];
      __builtin_amdgcn_s_setprio(1);
#pragma unroll
      for (int mf = 0; mf < 4; ++mf)
#pragma unroll
        for (int nf = 0; nf < 2; ++nf)
          acc[mf][nf] = mfma16(af[mf], bfr[nf], acc[mf][nf]);
      __builtin_amdgcn_s_setprio(0);
    }
  }

#pragma unroll
  for (int mf = 0; mf < 4; ++mf)
#pragma unroll
    for (int nf = 0; nf < 2; ++nf)
#pragma unroll
      for (int i = 0; i < 4; ++i)
        C[(size_t)(m0 + wr * 64 + mf * 16 + g * 4 + i) * N +
          n0 + wc * 32 + nf * 16 + l15] = acc[mf][nf][i];
}

// ---------------- flash sliding-window attention, QBLK=128, 8 waves, dbuf
__global__ __launch_bounds__(512) void attn_kernel(
    bf16_t* __restrict__ QKV, const bf16_t* __restrict__ Vt) {
  __shared__ __align__(16) bf16_t Kl[2][64 * 64];
  __shared__ __align__(16) bf16_t Vl[2][64 * 64];

  const int qt = ((blockIdx.x & 7) << 1) | (blockIdx.x >> 3);  // XCD-chunked, 16 qts
  const int bh = blockIdx.y;
  const int b = bh >> 4, h = bh & 15;
  const int q0 = qt * 128;
  const int tid = threadIdx.x, w = tid >> 6, lane = tid & 63;
  const int g = lane >> 4, l15 = lane & 15, gh = g >> 1;
  const int wrow0 = q0 + w * 16;
  const int myrow = wrow0 + l15;
  const int sub = lane >> 3, jj = lane & 7;
  const int sw = l15 & 7;

  // per-wave: 1 K chunk + 1 V chunk (8 waves cover the 64x64 tiles)
  auto stage = [&](int bufi, int kt) {
    const int row = w * 8 + sub;
    const int sj = jj ^ sub;
    gload_lds16(QKV + ((size_t)b * T_SZ + kt + row) * QKV_LD + 1024 + h * D_SZ + sj * 8,
                &Kl[bufi][w * 512]);
    gload_lds16(Vt + ((size_t)bh * D_SZ + row) * T_SZ + kt + sj * 8,
                &Vl[bufi][w * 512]);
  };

  bf16x8 qf[2];
  {
    const bf16_t* qptr = QKV + ((size_t)b * T_SZ + myrow) * QKV_LD + h * D_SZ;
    const float QSC = 0.125f * 1.44269504f;
#pragma unroll
    for (int c2 = 0; c2 < 2; ++c2) {
      bf16x8 t = *(const bf16x8*)(qptr + c2 * 32 + g * 8);
      bf16x8 o;
#pragma unroll
      for (int j = 0; j < 8; ++j) o[j] = (bf16_t)((float)t[j] * QSC);
      qf[c2] = o;
    }
  }

  float m_s = -1e30f, l_s = 0.f;
  f32x4 oacc[4] = {};

  int kstart = q0 - (WIN - 1);
  if (kstart < 0) kstart = 0;
  kstart &= ~63;
  const int nt = (q0 + 128 - kstart) >> 6;

  stage(0, kstart);

  for (int it = 0; it < nt; ++it) {
    const int kt = kstart + (it << 6);
    const int cur = it & 1;
    if (it + 1 < nt) {
      stage(cur ^ 1, kt + 64);
      asm volatile("s_waitcnt vmcnt(2)" ::: "memory");
    } else {
      asm volatile("s_waitcnt vmcnt(0)" ::: "memory");
    }
    __builtin_amdgcn_s_barrier();
    __builtin_amdgcn_sched_barrier(0);

    // wave-uniform: tile fully outside this wave's band -> skip compute
    const bool skip = (kt + 63 < wrow0 - (WIN - 1)) || (kt > wrow0 + 15);
    if (!skip) {
      f32x4 s[4] = {};
#pragma unroll
      for (int t = 0; t < 4; ++t) {
        const bf16_t* kbase = &Kl[cur][(t * 16 + l15) * 64];
#pragma unroll
        for (int c2 = 0; c2 < 2; ++c2) {
          const bf16x8 kf = *(const bf16x8*)(kbase + (((c2 * 4 + g) ^ sw) << 3));
          s[t] = mfma16(kf, qf[c2], s[t]);
        }
      }

      const bool interior = (kt + 63 <= wrow0) && (kt >= wrow0 + 15 - (WIN - 1));
      float sv[4][4];
      if (interior) {
#pragma unroll
        for (int t = 0; t < 4; ++t)
#pragma unroll
          for (int i = 0; i < 4; ++i) sv[t][i] = s[t][i];
      } else {
#pragma unroll
        for (int t = 0; t < 4; ++t)
#pragma unroll
          for (int i = 0; i < 4; ++i) {
            const int kk = kt + t * 16 + g * 4 + i;
            sv[t][i] = (kk <= myrow && kk > myrow - WIN) ? s[t][i] : -1e30f;
          }
      }

      float mx = sv[0][0];
#pragma unroll
      for (int t = 0; t < 4; ++t)
#pragma unroll
        for (int i = 0; i < 4; ++i)
          if (t || i) mx = fmaxf(mx, sv[t][i]);
      mx = fmaxf(mx, __shfl_xor(mx, 16));
      mx = fmaxf(mx, __shfl_xor(mx, 32));

      float mbase;
      const bool defer = __all((mx <= m_s + 8.f) && (m_s > -1e29f));
      if (defer) {
        mbase = m_s;
      } else {
        const float mnew = fmaxf(m_s, mx);
        const float scl = exp2f(m_s - mnew);
        m_s = mnew;
        mbase = (mnew > -1e29f) ? mnew : 1e30f;
        float sc4[4];
#pragma unroll
        for (int i = 0; i < 4; ++i) sc4[i] = __shfl(scl, g * 4 + i, 16);
#pragma unroll
        for (int c = 0; c < 4; ++c)
#pragma unroll
          for (int i = 0; i < 4; ++i) oacc[c][i] *= sc4[i];
        l_s *= scl;
      }

      float p[4][4];
      float rsum = 0.f;
#pragma unroll
      for (int t = 0; t < 4; ++t)
#pragma unroll
        for (int i = 0; i < 4; ++i) {
          p[t][i] = exp2f(sv[t][i] - mbase);
          rsum += p[t][i];
        }
      rsum += __shfl_xor(rsum, 16);
      rsum += __shfl_xor(rsum, 32);
      l_s += rsum;

      u32 Wp[4][2];
#pragma unroll
      for (int t = 0; t < 4; ++t)
#pragma unroll
        for (int w2 = 0; w2 < 2; ++w2) {
          union { bf16_t hh[2]; u32 uu; } pk;
          pk.hh[0] = (bf16_t)p[t][2 * w2];
          pk.hh[1] = (bf16_t)p[t][2 * w2 + 1];
          Wp[t][w2] = pk.uu;
        }

#pragma unroll
      for (int kp = 0; kp < 2; ++kp) {
        const u32 lo0 = Wp[2 * kp][0], lo1 = Wp[2 * kp][1];
        const u32 hi0 = Wp[2 * kp + 1][0], hi1 = Wp[2 * kp + 1][1];
        union { u32 u[4]; bf16x8 v; } pa;
        pa.u[0] = gh ? hi0 : lo0;
        pa.u[1] = gh ? hi1 : lo1;
        pa.u[2] = (u32)__shfl_xor((int)(gh ? lo0 : hi0), 32);
        pa.u[3] = (u32)__shfl_xor((int)(gh ? lo1 : hi1), 32);

        const int tA = 2 * kp + gh;
        const int low = (g & 1) * 4;
        const int cA = ((tA * 2 + gh) ^ sw) << 3;
        const int cB = ((tA * 2 + (gh ^ 1)) ^ sw) << 3;
#pragma unroll
        for (int c = 0; c < 4; ++c) {
          const bf16_t* vbase = &Vl[cur][(c * 16 + l15) * 64];
          union { bf16x4 h[2]; bf16x8 v; } vv;
          vv.h[0] = *(const bf16x4*)(vbase + cA + low);
          vv.h[1] = *(const bf16x4*)(vbase + cB + low);
          oacc[c] = mfma16(pa.v, vv.v, oacc[c]);
        }
      }
    }
    __builtin_amdgcn_sched_barrier(0);
    __builtin_amdgcn_s_barrier();
  }

  const float invl = 1.0f / l_s;
  float inv4[4];
#pragma unroll
  for (int i = 0; i < 4; ++i) inv4[i] = __shfl(invl, g * 4 + i, 16);
#pragma unroll
  for (int i = 0; i < 4; ++i) {
    const size_t ro = ((size_t)b * T_SZ + wrow0 + g * 4 + i) * QKV_LD + 2048 + h * D_SZ;
#pragma unroll
    for (int c = 0; c < 4; ++c)
      QKV[ro + c * 16 + l15] = (bf16_t)(oacc[c][i] * inv4[i]);
  }
}

extern "C" void kernel_launch(void* const* d_in, const int* in_sizes, int n_in,
                              void* d_out, int out_size, void* d_ws, size_t ws_size,
                              hipStream_t stream) {
  const float* x = (const float*)d_in[0];
  const float* Wq = (const float*)d_in[1];
  const float* Wk = (const float*)d_in[2];
  const float* Wv = (const float*)d_in[3];
  const float* Wo = (const float*)d_in[4];
  float* out = (float*)d_out;
  char* ws = (char*)d_ws;
  const size_t MB = 1ull << 20;
  bf16_t* xb = (bf16_t*)(ws);                // [4096][1024] bf16 x
  bf16_t* QKVb = (bf16_t*)(ws + 8 * MB);     // [4096][3072]; V-cols hold attn out
  bf16_t* WqT = (bf16_t*)(ws + 32 * MB);     // [3072][1024] combined (q|k|v)
  bf16_t* WkT = (bf16_t*)(ws + 34 * MB);
  bf16_t* WvT = (bf16_t*)(ws + 36 * MB);
  bf16_t* WoT = (bf16_t*)(ws + 38 * MB);
  bf16_t* Vtp = (bf16_t*)(ws + 48 * MB);     // Vt [32][64][2048]

  prep<<<dim3(32, 32, 5), 256, 0, stream>>>(x, xb, Wq, Wk, Wv, Wo,
                                            WqT, WkT, WvT, WoT);
  gemm256<<<dim3(16, 16), 512, 0, stream>>>(xb, WqT, QKVb, Vtp);
  attn_kernel<<<dim3(16, B_SZ * H_CNT), 512, 0, stream>>>(QKVb, Vtp);
  gemm128<<<dim3(8, 32), 512, 0, stream>>>(QKVb + 2048, QKV_LD, WoT, out, C_SZ);
}